// Round 3
// baseline (1967.870 us; speedup 1.0000x reference)
//
#include <hip/hip_runtime.h>
#include <math.h>

#define NB 8
#define CIn 32
#define COut 32
#define NIO 1024      // CIn*COut
#define NN1 256
#define NN2 256
#define NYF 129       // NN2/2+1
#define NK1 16
#define NK2 9
#define NKL 144       // NK1*NK2

typedef float2 c32;

__device__ __forceinline__ c32 cadd(c32 a, c32 b){ return make_float2(a.x+b.x, a.y+b.y); }
__device__ __forceinline__ c32 csub(c32 a, c32 b){ return make_float2(a.x-b.x, a.y-b.y); }
__device__ __forceinline__ c32 cmul(c32 a, c32 b){ return make_float2(a.x*b.x - a.y*b.y, a.x*b.y + a.y*b.x); }
__device__ __forceinline__ c32 cfma(c32 a, c32 b, c32 acc){
  acc.x = fmaf(a.x, b.x, acc.x); acc.x = fmaf(-a.y, b.y, acc.x);
  acc.y = fmaf(a.x, b.y, acc.y); acc.y = fmaf(a.y, b.x, acc.y);
  return acc;
}

// ---------------- FFT-256 via four-step radix-16 ----------------
template<int INV> __device__ __forceinline__ c32 rot90(c32 a){
  return INV ? make_float2(-a.y, a.x) : make_float2(a.y, -a.x);
}
template<int INV> __device__ __forceinline__ void dft4(c32& a0, c32& a1, c32& a2, c32& a3){
  c32 t0 = cadd(a0,a2), t1 = csub(a0,a2);
  c32 t2 = cadd(a1,a3), t3 = rot90<INV>(csub(a1,a3));
  a0 = cadd(t0,t2); a1 = cadd(t1,t3); a2 = csub(t0,t2); a3 = csub(t1,t3);
}
__device__ __forceinline__ int SLOT16(int k){ return 4*(k&3) + (k>>2); }
template<int INV> __device__ __forceinline__ c32 twg(const float2* ltw, int idx){
  float2 w = ltw[idx & 255];
  return INV ? make_float2(w.x, w.y) : make_float2(w.x, -w.y);
}
template<int INV> __device__ __forceinline__ void fft16r(c32 v[16], const float2* ltw){
#pragma unroll
  for (int bp = 0; bp < 4; bp++) dft4<INV>(v[bp], v[4+bp], v[8+bp], v[12+bp]);
#pragma unroll
  for (int c = 1; c < 4; c++)
#pragma unroll
    for (int bp = 1; bp < 4; bp++)
      v[4*c+bp] = cmul(v[4*c+bp], twg<INV>(ltw, 16*bp*c));
#pragma unroll
  for (int c = 0; c < 4; c++) dft4<INV>(v[4*c], v[4*c+1], v[4*c+2], v[4*c+3]);
}
template<int INV>
__device__ __forceinline__ void fft256_core(c32 v[16], int b, c32* tile, const float2* ltw){
  fft16r<INV>(v, ltw);
#pragma unroll
  for (int c = 0; c < 16; c++){
    c32 g = (c && b) ? cmul(v[SLOT16(c)], twg<INV>(ltw, b*c)) : v[SLOT16(c)];
    tile[c*17 + b] = g;
  }
  __syncthreads();
#pragma unroll
  for (int j = 0; j < 16; j++) v[j] = tile[b*17 + j];
  fft16r<INV>(v, ltw);
}

// ---------- precompute tables ----------
__global__ void k_tw(float2* __restrict__ tw){
  int m = threadIdx.x;
  double ang = 6.283185307179586 * (double)m / 256.0;
  tw[m] = make_float2((float)cos(ang), (float)sin(ang));
}

__global__ void k_p1(const float* __restrict__ p1r, const float* __restrict__ p1i, c32* __restrict__ P1){
  int idx = blockIdx.x * 256 + threadIdx.x;
  int x = idx & 255; int iok = idx >> 8;
  float f = (x < 128) ? (float)x : (float)(x - 256);
  float a = -p1r[iok];
  float b = 6.2831853071795864f * f - p1i[iok];
  float inv = 1.0f / fmaf(a, a, b * b);
  P1[idx] = make_float2(a * inv, -b * inv);
}

__global__ void k_p2(const float* __restrict__ p2r, const float* __restrict__ p2i, c32* __restrict__ P2){
  int idx = blockIdx.x * 256 + threadIdx.x;
  if (idx >= NIO * NK2 * NYF) return;
  int y = idx % NYF; int iol = idx / NYF;
  float a = -p2r[iol];
  float b = 6.2831853071795864f * (float)y - p2i[iol];
  float inv = 1.0f / fmaf(a, a, b * b);
  P2[idx] = make_float2(a * inv, -b * inv);
}

__global__ void k_e1(const float* __restrict__ p1r, const float* __restrict__ p1i, c32* __restrict__ E1){
  int idx = blockIdx.x * 256 + threadIdx.x;
  int z = idx & 255; int iok = idx >> 8;
  float t = (float)z * (1.0f / 256.0f);
  float er = expf(p1r[iok] * t);
  float s, c; sincosf(p1i[iok] * t, &s, &c);
  E1[idx] = make_float2(er * c, er * s);
}

__global__ void k_e2(const float* __restrict__ p2r, const float* __restrict__ p2i, c32* __restrict__ E2){
  int idx = blockIdx.x * 256 + threadIdx.x;
  int w = idx & 255; int iol = idx >> 8;
  float t = (float)w * (1.0f / 256.0f);
  float er = expf(p2r[iol] * t);
  float s, c; sincosf(p2i[iol] * t, &s, &c);
  E2[idx] = make_float2(er * c, er * s);
}

__global__ void k_R2(const float* __restrict__ rr, const float* __restrict__ ri,
                     const c32* __restrict__ P2, c32* __restrict__ R2){
  int idx = blockIdx.x * 256 + threadIdx.x;
  if (idx >= NIO * NK1 * NYF) return;
  int y = idx % NYF; int iok = idx / NYF; int io = iok >> 4;
  c32 acc = make_float2(0.0f, 0.0f);
#pragma unroll
  for (int l = 0; l < NK2; l++){
    c32 res = make_float2(rr[iok * NK2 + l], ri[iok * NK2 + l]);
    acc = cfma(res, P2[((size_t)io * NK2 + l) * NYF + y], acc);
  }
  R2[idx] = acc;
}

// ---------- forward: rfft along n2 (paired rows), write alpha[(bi*129+y)*256+n1], scaled 1/65536 ----------
__global__ __launch_bounds__(256) void k_fwd_y(const float* __restrict__ x, const float2* __restrict__ tw,
                                               c32* __restrict__ alpha){
  __shared__ c32 tile[16*272];
  __shared__ float2 ltw[256];
  int t = threadIdx.x;
  ltw[t] = tw[t];
  int bi = blockIdx.x >> 3;
  int n1c = (blockIdx.x & 7) << 5;
  int row = t >> 4, b = t & 15;
  const float* xe = x + ((size_t)bi * 256 + n1c + 2 * row) * 256;
  c32 v[16];
#pragma unroll
  for (int a = 0; a < 16; a++)
    v[a] = make_float2(xe[16*a + b], xe[256 + 16*a + b]);
  __syncthreads();
  fft256_core<0>(v, b, tile + row*272, ltw);
  __syncthreads();
#pragma unroll
  for (int d = 0; d < 16; d++)
    tile[row*272 + b + 16*d] = v[SLOT16(d)];
  __syncthreads();
  const float sc = 0.5f / 65536.0f;
#pragma unroll
  for (int j = 0; j < 8; j++){
    int item = t + 256*j;
    int h = item & 127, r2 = item >> 7;
    c32* Zb = tile + r2*272;
    if (h == 0){
      c32 z0 = Zb[0], z1 = Zb[128];
      Zb[0]   = make_float2(z0.x * (2.0f*sc), z0.y * (2.0f*sc));
      Zb[128] = make_float2(z1.x * (2.0f*sc), z1.y * (2.0f*sc));
    } else {
      c32 zk = Zb[h], zm = Zb[256 - h];
      c32 A = make_float2(sc*(zk.x + zm.x), sc*(zk.y - zm.y));
      c32 B = make_float2(sc*(zk.y + zm.y), sc*(zm.x - zk.x));
      Zb[h] = A; Zb[256 - h] = B;
    }
  }
  __syncthreads();
  for (int j = 0; j < 17; j++){
    int idx = t + 256*j;
    if (idx >= 129*32) break;
    int y = idx >> 5, n1i = idx & 31;
    c32* Zb = tile + (n1i >> 1)*272;
    c32 val;
    if ((n1i & 1) == 0)
      val = (y == 0) ? make_float2(Zb[0].x, 0.0f)
          : (y == 128) ? make_float2(Zb[128].x, 0.0f) : Zb[y];
    else
      val = (y == 0) ? make_float2(Zb[0].y, 0.0f)
          : (y == 128) ? make_float2(Zb[128].y, 0.0f) : Zb[256 - y];
    alpha[((size_t)bi * 129 + y) * 256 + n1c + n1i] = val;
  }
}

// ---------- complex FFT-256 on contiguous rows, in place ----------
template<int INV>
__global__ __launch_bounds__(256) void k_fft_x(const float2* __restrict__ tw, c32* __restrict__ buf){
  __shared__ c32 tile[16*272];
  __shared__ float2 ltw[256];
  int t = threadIdx.x;
  ltw[t] = tw[t];
  int row = t >> 4, b = t & 15;
  c32* p = buf + ((size_t)blockIdx.x * 16 + row) * 256;
  c32 v[16];
#pragma unroll
  for (int a = 0; a < 16; a++) v[a] = p[16*a + b];
  __syncthreads();
  fft256_core<INV>(v, b, tile + row*272, ltw);
#pragma unroll
  for (int d = 0; d < 16; d++) p[b + 16*d] = v[SLOT16(d)];
}

// ---------- inverse rfft along y (paired z-columns) + bias, writes out ----------
__global__ __launch_bounds__(256) void k_inv_y(const c32* __restrict__ r1, const float* __restrict__ bias,
                                               const float2* __restrict__ tw, float* __restrict__ out){
  __shared__ c32 tile[16*272];
  __shared__ float2 ltw[256];
  c32* SA = tile;
  int t = threadIdx.x;
  ltw[t] = tw[t];
  int bo = blockIdx.x >> 3;
  int z0 = (blockIdx.x & 7) << 5;
  for (int j = 0; j < 17; j++){
    int idx = t + 256*j;
    if (idx >= 129*32) break;
    int y = idx >> 5, zi = idx & 31;
    SA[y*33 + zi] = r1[((size_t)bo * 129 + y) * 256 + z0 + zi];
  }
  __syncthreads();
  int p = t >> 4, b = t & 15;
  c32 v[16];
#pragma unroll
  for (int a = 0; a < 16; a++){
    int k = 16*a + b;
    int m = (k <= 128) ? k : 256 - k;
    c32 A = SA[m*33 + 2*p], B = SA[m*33 + 2*p + 1];
    if (k == 0 || k == 128)  v[a] = make_float2(A.x, B.x);
    else if (k < 128)        v[a] = make_float2(A.x - B.y, A.y + B.x);
    else                     v[a] = make_float2(A.x + B.y, B.x - A.y);
  }
  __syncthreads();
  fft256_core<1>(v, b, tile + p*272, ltw);
  float bv = bias[bo & 31];
  float* o0 = out + ((size_t)bo * 256 + z0 + 2*p) * 256;
#pragma unroll
  for (int d = 0; d < 16; d++){
    c32 zz = v[SLOT16(d)];
    o0[b + 16*d]       = zz.x + bv;
    o0[256 + b + 16*d] = zz.y + bv;
  }
}

// ---------- mode mixing: r1[b,o,y,x] = sum_i alpha * Hw ; y-major grid + XCD grouping ----------
__global__ __launch_bounds__(256) void k_r1(const c32* __restrict__ alpha, const c32* __restrict__ P1,
                                            const c32* __restrict__ R2, c32* __restrict__ r1){
  int x = threadIdx.x;
  int j = blockIdx.x;                       // 4128 = 8*516
  int orig = (j & 7) * 516 + (j >> 3);      // XCD-grouped: same-y blocks adjacent per XCD
  int y = orig >> 5, o = orig & 31;
  c32 acc[NB];
#pragma unroll
  for (int b = 0; b < NB; b++) acc[b] = make_float2(0.0f, 0.0f);
  for (int i = 0; i < CIn; i++){
    int io = i * COut + o;
    c32 hw = make_float2(0.0f, 0.0f);
    const c32* p1p = P1 + (size_t)io * NK1 * 256 + x;
    const c32* r2p = R2 + (size_t)io * NK1 * NYF + y;
#pragma unroll
    for (int k = 0; k < NK1; k++)
      hw = cfma(p1p[(size_t)k * 256], r2p[(size_t)k * NYF], hw);
#pragma unroll
    for (int b = 0; b < NB; b++){
      c32 a = alpha[(((size_t)b * CIn + i) * NYF + y) * 256 + x];
      acc[b] = cfma(a, hw, acc[b]);
    }
  }
#pragma unroll
  for (int b = 0; b < NB; b++)
    r1[(((size_t)b * COut + o) * NYF + y) * 256 + x] = acc[b];
}

// ---------- r2[b,io,k,l] ; XCD-grouped so 32 same-bi blocks share one XCD's L2 ----------
__global__ __launch_bounds__(256) void k_r2k(const c32* __restrict__ alpha, const c32* __restrict__ P1,
                                             const c32* __restrict__ P2,
                                             const float* __restrict__ rr, const float* __restrict__ ri,
                                             c32* __restrict__ r2){
  __shared__ float Tr[NK2][257], Ti[NK2][257];
  __shared__ float P2r[NK2][NYF], P2i[NK2][NYF];
  int t = threadIdx.x;
  int j = blockIdx.x;                       // 8192 = 8*1024
  int orig = (j & 7) * 1024 + (j >> 3);
  int o = orig & 31; int bi = orig >> 5;
  int i = bi & 31;  int b = bi >> 5;
  int io = i * COut + o;
  for (int s = t; s < NK2 * NYF; s += 256){
    c32 v = P2[(size_t)io * NK2 * NYF + s];
    int l = s / NYF, y = s - l * NYF;
    P2r[l][y] = v.x; P2i[l][y] = v.y;
  }
  __syncthreads();
  {
    float tr[NK2], ti[NK2];
#pragma unroll
    for (int l = 0; l < NK2; l++){ tr[l] = 0.0f; ti[l] = 0.0f; }
    const c32* ap = alpha + (size_t)bi * NYF * 256 + t;
    for (int y = 0; y < NYF; y++){
      c32 a = ap[(size_t)y * 256];
#pragma unroll
      for (int l = 0; l < NK2; l++){
        float c = P2r[l][y], s2 = P2i[l][y];
        tr[l] = fmaf(a.x, c, tr[l]); tr[l] = fmaf(-a.y, s2, tr[l]);
        ti[l] = fmaf(a.x, s2, ti[l]); ti[l] = fmaf(a.y, c, ti[l]);
      }
    }
#pragma unroll
    for (int l = 0; l < NK2; l++){ Tr[l][t] = tr[l]; Ti[l][t] = ti[l]; }
  }
  __syncthreads();
  if (t < NKL){
    int k = t / NK2, l = t - k * NK2;
    const c32* p1p = P1 + ((size_t)io * NK1 + k) * 256;
    float gr = 0.0f, gi = 0.0f;
#pragma unroll 4
    for (int xx = 0; xx < 256; xx++){
      c32 p = p1p[xx];
      float trv = Tr[l][xx], tiv = Ti[l][xx];
      gr = fmaf(p.x, trv, gr); gr = fmaf(-p.y, tiv, gr);
      gi = fmaf(p.x, tiv, gi); gi = fmaf( p.y, trv, gi);
    }
    float resr = rr[((size_t)io * NK1 + k) * NK2 + l];
    float resi = ri[((size_t)io * NK1 + k) * NK2 + l];
    float outr = -(resr * gr - resi * gi);
    float outi = -(resr * gi + resi * gr);
    r2[((size_t)b * NIO + io) * NKL + t] = make_float2(outr, outi);
  }
}

// ---------- x2 as fused register-blocked GEMM ----------
// block = (o, b, zhalf): C[128z x 256w] += Re( S'[il, z] * E2[il, w] ), K = 288 il.
// S' chunk computed on the fly from r2 & E1 into padded LDS A-tile.
__global__ __launch_bounds__(256) void k_x2g(const c32* __restrict__ r2, const c32* __restrict__ E1,
                                             const c32* __restrict__ E2, float* __restrict__ out){
  __shared__ c32 Asub[16*144];   // [kk][16 groups of 8, pad 9]
  __shared__ c32 Bsub[16*272];   // [kk][16 groups of 16, pad 17]
  int t = threadIdx.x;
  int j = blockIdx.x;                       // 512 = 8 XCD * 64
  int orig = (j & 7) * 64 + (j >> 3);       // per XCD: 4 consecutive o values
  int o = orig >> 4; int rem = orig & 15;
  int b = rem >> 1, zh = rem & 1;
  int z0 = zh * 128;
  int tzg = t >> 4, twg = t & 15;           // per-thread 8z x 16w micro-tile
  int srow = t >> 4, scol = t & 15;         // staging roles

  float acc[8][16];
#pragma unroll
  for (int m = 0; m < 8; m++)
#pragma unroll
    for (int n = 0; n < 16; n++) acc[m][n] = 0.0f;

  for (int c = 0; c < 18; c++){
    __syncthreads();
    int il = c*16 + srow;
    int i = (il * 7282) >> 16;              // il/9
    int l = il - 9*i;
    int io = i * COut + o;
    // stage B: E2 row il, w = scol*16..+15
    {
      const float4* s4 = (const float4*)(E2 + ((size_t)io * NK2 + l) * 256 + scol*16);
      float4* d4 = (float4*)(Bsub + srow*272 + scol*17);
#pragma unroll
      for (int q = 0; q < 8; q++) d4[q] = s4[q];
    }
    // compute A (S'): thread handles z = z0 + scol*8 .. +7 for row il
    {
      const c32* r2p = r2 + ((size_t)b * NIO + io) * NKL + l;
      const c32* e1p = E1 + (size_t)io * NK1 * 256 + z0 + scol*8;
      c32 s[8];
#pragma unroll
      for (int q = 0; q < 8; q++) s[q] = make_float2(0.0f, 0.0f);
#pragma unroll
      for (int k = 0; k < NK1; k++){
        c32 rv = r2p[k*9];
        const c32* ep = e1p + k*256;
#pragma unroll
        for (int q = 0; q < 8; q++) s[q] = cfma(rv, ep[q], s[q]);
      }
      c32* dst = Asub + srow*144 + scol*9;
#pragma unroll
      for (int q = 0; q < 8; q++) dst[q] = s[q];
    }
    __syncthreads();
    // GEMM consume
#pragma unroll
    for (int kk = 0; kk < 16; kk++){
      c32 af[8]; c32 bf[16];
      const c32* ap = Asub + kk*144 + tzg*9;
      const c32* bp = Bsub + kk*272 + twg*17;
#pragma unroll
      for (int q = 0; q < 8; q++) af[q] = ap[q];
#pragma unroll
      for (int q = 0; q < 16; q++) bf[q] = bp[q];
#pragma unroll
      for (int m = 0; m < 8; m++)
#pragma unroll
        for (int n = 0; n < 16; n++){
          acc[m][n] = fmaf(af[m].x, bf[n].x, acc[m][n]);
          acc[m][n] = fmaf(-af[m].y, bf[n].y, acc[m][n]);
        }
    }
  }
  // epilogue: out[b,o, z0+tzg*8+m, twg*16+n] += acc
  size_t base = (((size_t)(b * COut + o) * 256) + z0 + tzg*8) * 256 + twg*16;
#pragma unroll
  for (int m = 0; m < 8; m++){
    float4* o4 = (float4*)(out + base + (size_t)m * 256);
#pragma unroll
    for (int q = 0; q < 4; q++){
      float4 v = o4[q];
      v.x += acc[m][4*q+0]; v.y += acc[m][4*q+1];
      v.z += acc[m][4*q+2]; v.w += acc[m][4*q+3];
      o4[q] = v;
    }
  }
}

extern "C" void kernel_launch(void* const* d_in, const int* in_sizes, int n_in,
                              void* d_out, int out_size, void* d_ws, size_t ws_size,
                              hipStream_t stream){
  const float* x    = (const float*)d_in[0];
  const float* rr   = (const float*)d_in[1];
  const float* ri   = (const float*)d_in[2];
  const float* p1r  = (const float*)d_in[3];
  const float* p1i  = (const float*)d_in[4];
  const float* p2r  = (const float*)d_in[5];
  const float* p2i  = (const float*)d_in[6];
  const float* bias = (const float*)d_in[7];
  float* out = (float*)d_out;

  char* ws = (char*)d_ws;
  size_t off = 0;
  c32* alpha = (c32*)(ws + off); off += (size_t)NB * CIn * NYF * NN1 * sizeof(c32);
  c32* r1b   = (c32*)(ws + off); off += (size_t)NB * COut * NYF * NN1 * sizeof(c32);
  c32* P1    = (c32*)(ws + off); off += (size_t)NIO * NK1 * NN1 * sizeof(c32);
  c32* P2b   = (c32*)(ws + off); off += (size_t)NIO * NK2 * NYF * sizeof(c32);
  c32* R2b   = (c32*)(ws + off); off += (size_t)NIO * NK1 * NYF * sizeof(c32);
  c32* E1b   = (c32*)(ws + off); off += (size_t)NIO * NK1 * NN1 * sizeof(c32);
  c32* E2b   = (c32*)(ws + off); off += (size_t)NIO * NK2 * NN2 * sizeof(c32);
  c32* r2b   = (c32*)(ws + off); off += (size_t)NB * NIO * NKL * sizeof(c32);
  float2* tw = (float2*)(ws + off); off += 256 * sizeof(float2);

  k_tw<<<1, 256, 0, stream>>>(tw);
  k_p1<<<NIO * NK1, 256, 0, stream>>>(p1r, p1i, P1);
  k_p2<<<(NIO * NK2 * NYF + 255) / 256, 256, 0, stream>>>(p2r, p2i, P2b);
  k_e1<<<NIO * NK1, 256, 0, stream>>>(p1r, p1i, E1b);
  k_e2<<<NIO * NK2, 256, 0, stream>>>(p2r, p2i, E2b);
  k_R2<<<(NIO * NK1 * NYF + 255) / 256, 256, 0, stream>>>(rr, ri, P2b, R2b);

  k_fwd_y<<<NB * CIn * 8, 256, 0, stream>>>(x, tw, alpha);
  k_fft_x<0><<<NB * CIn * NYF / 16, 256, 0, stream>>>(tw, alpha);

  k_r1<<<COut * NYF, 256, 0, stream>>>(alpha, P1, R2b, r1b);
  k_r2k<<<NB * CIn * COut, 256, 0, stream>>>(alpha, P1, P2b, rr, ri, r2b);

  k_fft_x<1><<<NB * COut * NYF / 16, 256, 0, stream>>>(tw, r1b);
  k_inv_y<<<NB * COut * 8, 256, 0, stream>>>(r1b, bias, tw, out);

  k_x2g<<<512, 256, 0, stream>>>(r2b, E1b, E2b, out);
}

// Round 5
// 1614.301 us; speedup vs baseline: 1.2190x; 1.2190x over previous
//
#include <hip/hip_runtime.h>
#include <math.h>

#define NB 8
#define CIn 32
#define COut 32
#define NIO 1024      // CIn*COut
#define NN1 256
#define NN2 256
#define NYF 129       // NN2/2+1
#define NK1 16
#define NK2 9
#define NKL 144       // NK1*NK2

typedef float2 c32;
typedef __attribute__((ext_vector_type(8))) __bf16 bf16x8;
typedef __attribute__((ext_vector_type(4))) float f32x4;

__device__ __forceinline__ c32 cadd(c32 a, c32 b){ return make_float2(a.x+b.x, a.y+b.y); }
__device__ __forceinline__ c32 csub(c32 a, c32 b){ return make_float2(a.x-b.x, a.y-b.y); }
__device__ __forceinline__ c32 cmul(c32 a, c32 b){ return make_float2(a.x*b.x - a.y*b.y, a.x*b.y + a.y*b.x); }
__device__ __forceinline__ c32 cfma(c32 a, c32 b, c32 acc){
  acc.x = fmaf(a.x, b.x, acc.x); acc.x = fmaf(-a.y, b.y, acc.x);
  acc.y = fmaf(a.x, b.y, acc.y); acc.y = fmaf(a.y, b.x, acc.y);
  return acc;
}
__device__ __forceinline__ unsigned short f2bf(float f){
  unsigned int u = __float_as_uint(f);
  u += 0x7FFF + ((u >> 16) & 1);
  return (unsigned short)(u >> 16);
}
__device__ __forceinline__ float bf2f(unsigned short h){
  unsigned int u = ((unsigned int)h) << 16;
  return __uint_as_float(u);
}
// pack value into (hi, lo) bf16 halves: hi+lo ~ 16-bit-mantissa approx of f
__device__ __forceinline__ void split_bf(float f, unsigned short& hi, unsigned short& lo){
  hi = f2bf(f);
  lo = f2bf(f - bf2f(hi));
}

#define GLOAD16(lptr, gptr) \
  __builtin_amdgcn_global_load_lds((const __attribute__((address_space(1))) unsigned int*)(gptr), \
                                   (__attribute__((address_space(3))) unsigned int*)(lptr), 16, 0, 0)

// ---------------- FFT-256 via four-step radix-16 ----------------
template<int INV> __device__ __forceinline__ c32 rot90(c32 a){
  return INV ? make_float2(-a.y, a.x) : make_float2(a.y, -a.x);
}
template<int INV> __device__ __forceinline__ void dft4(c32& a0, c32& a1, c32& a2, c32& a3){
  c32 t0 = cadd(a0,a2), t1 = csub(a0,a2);
  c32 t2 = cadd(a1,a3), t3 = rot90<INV>(csub(a1,a3));
  a0 = cadd(t0,t2); a1 = cadd(t1,t3); a2 = csub(t0,t2); a3 = csub(t1,t3);
}
__device__ __forceinline__ int SLOT16(int k){ return 4*(k&3) + (k>>2); }
template<int INV> __device__ __forceinline__ c32 twg(const float2* ltw, int idx){
  float2 w = ltw[idx & 255];
  return INV ? make_float2(w.x, w.y) : make_float2(w.x, -w.y);
}
template<int INV> __device__ __forceinline__ void fft16r(c32 v[16], const float2* ltw){
#pragma unroll
  for (int bp = 0; bp < 4; bp++) dft4<INV>(v[bp], v[4+bp], v[8+bp], v[12+bp]);
#pragma unroll
  for (int c = 1; c < 4; c++)
#pragma unroll
    for (int bp = 1; bp < 4; bp++)
      v[4*c+bp] = cmul(v[4*c+bp], twg<INV>(ltw, 16*bp*c));
#pragma unroll
  for (int c = 0; c < 4; c++) dft4<INV>(v[4*c], v[4*c+1], v[4*c+2], v[4*c+3]);
}
template<int INV>
__device__ __forceinline__ void fft256_core(c32 v[16], int b, c32* tile, const float2* ltw){
  fft16r<INV>(v, ltw);
#pragma unroll
  for (int c = 0; c < 16; c++){
    c32 g = (c && b) ? cmul(v[SLOT16(c)], twg<INV>(ltw, b*c)) : v[SLOT16(c)];
    tile[c*17 + b] = g;
  }
  __syncthreads();
#pragma unroll
  for (int j = 0; j < 16; j++) v[j] = tile[b*17 + j];
  fft16r<INV>(v, ltw);
}

// ---------- precompute tables ----------
__global__ void k_tw(float2* __restrict__ tw){
  int m = threadIdx.x;
  double ang = 6.283185307179586 * (double)m / 256.0;
  tw[m] = make_float2((float)cos(ang), (float)sin(ang));
}

__global__ void k_p1(const float* __restrict__ p1r, const float* __restrict__ p1i, c32* __restrict__ P1){
  int idx = blockIdx.x * 256 + threadIdx.x;
  int x = idx & 255; int iok = idx >> 8;
  float f = (x < 128) ? (float)x : (float)(x - 256);
  float a = -p1r[iok];
  float b = 6.2831853071795864f * f - p1i[iok];
  float inv = 1.0f / fmaf(a, a, b * b);
  P1[idx] = make_float2(a * inv, -b * inv);
}

__global__ void k_p2(const float* __restrict__ p2r, const float* __restrict__ p2i, c32* __restrict__ P2){
  int idx = blockIdx.x * 256 + threadIdx.x;
  if (idx >= NIO * NK2 * NYF) return;
  int y = idx % NYF; int iol = idx / NYF;
  float a = -p2r[iol];
  float b = 6.2831853071795864f * (float)y - p2i[iol];
  float inv = 1.0f / fmaf(a, a, b * b);
  P2[idx] = make_float2(a * inv, -b * inv);
}

__global__ void k_e1(const float* __restrict__ p1r, const float* __restrict__ p1i, c32* __restrict__ E1){
  int idx = blockIdx.x * 256 + threadIdx.x;
  int z = idx & 255; int iok = idx >> 8;
  float t = (float)z * (1.0f / 256.0f);
  float er = expf(p1r[iok] * t);
  float s, c; sincosf(p1i[iok] * t, &s, &c);
  E1[idx] = make_float2(er * c, er * s);
}

__global__ void k_R2(const float* __restrict__ rr, const float* __restrict__ ri,
                     const c32* __restrict__ P2, c32* __restrict__ R2){
  int idx = blockIdx.x * 256 + threadIdx.x;
  if (idx >= NIO * NK1 * NYF) return;
  int y = idx % NYF; int iok = idx / NYF; int io = iok >> 4;
  c32 acc = make_float2(0.0f, 0.0f);
#pragma unroll
  for (int l = 0; l < NK2; l++){
    c32 res = make_float2(rr[iok * NK2 + l], ri[iok * NK2 + l]);
    acc = cfma(res, P2[((size_t)io * NK2 + l) * NYF + y], acc);
  }
  R2[idx] = acc;
}

// ---------- forward: rfft along n2 (paired rows), write alpha[(bi*129+y)*256+n1], scaled 1/65536 ----------
__global__ __launch_bounds__(256) void k_fwd_y(const float* __restrict__ x, const float2* __restrict__ tw,
                                               c32* __restrict__ alpha){
  __shared__ c32 tile[16*272];
  __shared__ float2 ltw[256];
  int t = threadIdx.x;
  ltw[t] = tw[t];
  int bi = blockIdx.x >> 3;
  int n1c = (blockIdx.x & 7) << 5;
  int row = t >> 4, b = t & 15;
  const float* xe = x + ((size_t)bi * 256 + n1c + 2 * row) * 256;
  c32 v[16];
#pragma unroll
  for (int a = 0; a < 16; a++)
    v[a] = make_float2(xe[16*a + b], xe[256 + 16*a + b]);
  __syncthreads();
  fft256_core<0>(v, b, tile + row*272, ltw);
  __syncthreads();
#pragma unroll
  for (int d = 0; d < 16; d++)
    tile[row*272 + b + 16*d] = v[SLOT16(d)];
  __syncthreads();
  const float sc = 0.5f / 65536.0f;
#pragma unroll
  for (int j = 0; j < 8; j++){
    int item = t + 256*j;
    int h = item & 127, r2 = item >> 7;
    c32* Zb = tile + r2*272;
    if (h == 0){
      c32 z0 = Zb[0], z1 = Zb[128];
      Zb[0]   = make_float2(z0.x * (2.0f*sc), z0.y * (2.0f*sc));
      Zb[128] = make_float2(z1.x * (2.0f*sc), z1.y * (2.0f*sc));
    } else {
      c32 zk = Zb[h], zm = Zb[256 - h];
      c32 A = make_float2(sc*(zk.x + zm.x), sc*(zk.y - zm.y));
      c32 B = make_float2(sc*(zk.y + zm.y), sc*(zm.x - zk.x));
      Zb[h] = A; Zb[256 - h] = B;
    }
  }
  __syncthreads();
  for (int j = 0; j < 17; j++){
    int idx = t + 256*j;
    if (idx >= 129*32) break;
    int y = idx >> 5, n1i = idx & 31;
    c32* Zb = tile + (n1i >> 1)*272;
    c32 val;
    if ((n1i & 1) == 0)
      val = (y == 0) ? make_float2(Zb[0].x, 0.0f)
          : (y == 128) ? make_float2(Zb[128].x, 0.0f) : Zb[y];
    else
      val = (y == 0) ? make_float2(Zb[0].y, 0.0f)
          : (y == 128) ? make_float2(Zb[128].y, 0.0f) : Zb[256 - y];
    alpha[((size_t)bi * 129 + y) * 256 + n1c + n1i] = val;
  }
}

// ---------- complex FFT-256 on contiguous rows, in place ----------
template<int INV>
__global__ __launch_bounds__(256) void k_fft_x(const float2* __restrict__ tw, c32* __restrict__ buf){
  __shared__ c32 tile[16*272];
  __shared__ float2 ltw[256];
  int t = threadIdx.x;
  ltw[t] = tw[t];
  int row = t >> 4, b = t & 15;
  c32* p = buf + ((size_t)blockIdx.x * 16 + row) * 256;
  c32 v[16];
#pragma unroll
  for (int a = 0; a < 16; a++) v[a] = p[16*a + b];
  __syncthreads();
  fft256_core<INV>(v, b, tile + row*272, ltw);
#pragma unroll
  for (int d = 0; d < 16; d++) p[b + 16*d] = v[SLOT16(d)];
}

// ---------- inverse rfft along y (paired z-columns) + bias, writes out ----------
__global__ __launch_bounds__(256) void k_inv_y(const c32* __restrict__ r1, const float* __restrict__ bias,
                                               const float2* __restrict__ tw, float* __restrict__ out){
  __shared__ c32 tile[16*272];
  __shared__ float2 ltw[256];
  c32* SA = tile;
  int t = threadIdx.x;
  ltw[t] = tw[t];
  int bo = blockIdx.x >> 3;
  int z0 = (blockIdx.x & 7) << 5;
  for (int j = 0; j < 17; j++){
    int idx = t + 256*j;
    if (idx >= 129*32) break;
    int y = idx >> 5, zi = idx & 31;
    SA[y*33 + zi] = r1[((size_t)bo * 129 + y) * 256 + z0 + zi];
  }
  __syncthreads();
  int p = t >> 4, b = t & 15;
  c32 v[16];
#pragma unroll
  for (int a = 0; a < 16; a++){
    int k = 16*a + b;
    int m = (k <= 128) ? k : 256 - k;
    c32 A = SA[m*33 + 2*p], B = SA[m*33 + 2*p + 1];
    if (k == 0 || k == 128)  v[a] = make_float2(A.x, B.x);
    else if (k < 128)        v[a] = make_float2(A.x - B.y, A.y + B.x);
    else                     v[a] = make_float2(A.x + B.y, B.x - A.y);
  }
  __syncthreads();
  fft256_core<1>(v, b, tile + p*272, ltw);
  float bv = bias[bo & 31];
  float* o0 = out + ((size_t)bo * 256 + z0 + 2*p) * 256;
#pragma unroll
  for (int d = 0; d < 16; d++){
    c32 zz = v[SLOT16(d)];
    o0[b + 16*d]       = zz.x + bv;
    o0[256 + b + 16*d] = zz.y + bv;
  }
}

// ---------- mode mixing ----------
__global__ __launch_bounds__(256) void k_r1(const c32* __restrict__ alpha, const c32* __restrict__ P1,
                                            const c32* __restrict__ R2, c32* __restrict__ r1){
  int x = threadIdx.x;
  int bid = blockIdx.x;           // o*129 + y
  int o = bid / NYF, y = bid - o * NYF;
  c32 acc[NB];
#pragma unroll
  for (int b = 0; b < NB; b++) acc[b] = make_float2(0.0f, 0.0f);
  for (int i = 0; i < CIn; i++){
    int io = i * COut + o;
    c32 hw = make_float2(0.0f, 0.0f);
    const c32* p1p = P1 + (size_t)io * NK1 * 256 + x;
    const c32* r2p = R2 + (size_t)io * NK1 * NYF + y;
#pragma unroll
    for (int k = 0; k < NK1; k++)
      hw = cfma(p1p[(size_t)k * 256], r2p[(size_t)k * NYF], hw);
#pragma unroll
    for (int b = 0; b < NB; b++){
      c32 a = alpha[(((size_t)b * CIn + i) * NYF + y) * 256 + x];
      acc[b] = cfma(a, hw, acc[b]);
    }
  }
#pragma unroll
  for (int b = 0; b < NB; b++)
    r1[(((size_t)b * COut + o) * NYF + y) * 256 + x] = acc[b];
}

__global__ __launch_bounds__(256) void k_r2k(const c32* __restrict__ alpha, const c32* __restrict__ P1,
                                             const c32* __restrict__ P2,
                                             const float* __restrict__ rr, const float* __restrict__ ri,
                                             c32* __restrict__ r2){
  __shared__ float Tr[NK2][257], Ti[NK2][257];
  __shared__ float P2r[NK2][NYF], P2i[NK2][NYF];
  int t = threadIdx.x;
  int bid = blockIdx.x;             // (b*CI+i)*CO + o
  int o = bid & 31; int bi = bid >> 5;
  int i = bi & 31;  int b = bi >> 5;
  int io = i * COut + o;
  for (int s = t; s < NK2 * NYF; s += 256){
    c32 v = P2[(size_t)io * NK2 * NYF + s];
    int l = s / NYF, y = s - l * NYF;
    P2r[l][y] = v.x; P2i[l][y] = v.y;
  }
  __syncthreads();
  {
    float tr[NK2], ti[NK2];
#pragma unroll
    for (int l = 0; l < NK2; l++){ tr[l] = 0.0f; ti[l] = 0.0f; }
    const c32* ap = alpha + (size_t)bi * NYF * 256 + t;
    for (int y = 0; y < NYF; y++){
      c32 a = ap[(size_t)y * 256];
#pragma unroll
      for (int l = 0; l < NK2; l++){
        float c = P2r[l][y], s2 = P2i[l][y];
        tr[l] = fmaf(a.x, c, tr[l]); tr[l] = fmaf(-a.y, s2, tr[l]);
        ti[l] = fmaf(a.x, s2, ti[l]); ti[l] = fmaf(a.y, c, ti[l]);
      }
    }
#pragma unroll
    for (int l = 0; l < NK2; l++){ Tr[l][t] = tr[l]; Ti[l][t] = ti[l]; }
  }
  __syncthreads();
  if (t < NKL){
    int k = t / NK2, l = t - k * NK2;
    const c32* p1p = P1 + ((size_t)io * NK1 + k) * 256;
    float gr = 0.0f, gi = 0.0f;
#pragma unroll 4
    for (int xx = 0; xx < 256; xx++){
      c32 p = p1p[xx];
      float trv = Tr[l][xx], tiv = Ti[l][xx];
      gr = fmaf(p.x, trv, gr); gr = fmaf(-p.y, tiv, gr);
      gi = fmaf(p.x, tiv, gi); gi = fmaf( p.y, trv, gi);
    }
    float resr = rr[((size_t)io * NK1 + k) * NK2 + l];
    float resi = ri[((size_t)io * NK1 + k) * NK2 + l];
    float outr = -(resr * gr - resi * gi);
    float outi = -(resr * gi + resi * gr);
    r2[((size_t)b * NIO + io) * NKL + t] = make_float2(outr, outi);
  }
}

// ---------- x2 path: split-bf16 MFMA GEMM pipeline ----------
// B': rows of 1152 halves = [B_hi (576) | B_lo (576)], kap = 2*(i*9+l)+c : c=0 -> E2r, c=1 -> -E2i
__global__ __launch_bounds__(256) void k_e2b(const float* __restrict__ p2r, const float* __restrict__ p2i,
                                             unsigned int* __restrict__ B){
  int o = blockIdx.x, w = threadIdx.x;
  float tt = (float)w * (1.0f / 256.0f);
  unsigned int* brow = B + ((size_t)o * 256 + w) * 576;   // 576 uints = 1152 halves
  for (int i = 0; i < 32; i++){
    int io = i * 32 + o;
#pragma unroll
    for (int l = 0; l < 9; l++){
      float pr = p2r[io*9 + l], pi = p2i[io*9 + l];
      float er = expf(pr * tt);
      float s, c; sincosf(pi * tt, &s, &c);
      float vr = er * c, vi = -er * s;
      unsigned short rh, rl, ih, il;
      split_bf(vr, rh, rl); split_bf(vi, ih, il);
      brow[i*9 + l]       = (unsigned int)rh | ((unsigned int)ih << 16);
      brow[288 + i*9 + l] = (unsigned int)rl | ((unsigned int)il << 16);
    }
  }
}

// A_hi/A_lo: [o][m=(b*256+z)][576 halves], V[b,io,l,z] = sum_k r2[b,io,k,l]*E1[io,k,z]
__global__ __launch_bounds__(256) void k_v(const c32* __restrict__ r2, const c32* __restrict__ E1,
                                           unsigned int* __restrict__ Ahi, unsigned int* __restrict__ Alo){
  int t = threadIdx.x;                 // z
  int j = blockIdx.x;                  // 256 = 8 xcd * 32
  int o = (j & 7) * 4 + ((j >> 3) & 3);
  int b = j >> 5;
  size_t rowoff = ((size_t)o * 2048 + b * 256 + t) * 288;
  unsigned int* AH = Ahi + rowoff;
  unsigned int* AL = Alo + rowoff;
  for (int i = 0; i < 32; i++){
    int io = i * 32 + o;
    const c32* e1p = E1 + (size_t)io * 16 * 256 + t;
    c32 e[16];
#pragma unroll
    for (int k = 0; k < 16; k++) e[k] = e1p[(size_t)k * 256];
    const c32* rp = r2 + ((size_t)b * NIO + io) * NKL;
#pragma unroll
    for (int l = 0; l < 9; l++){
      c32 acc = make_float2(0.0f, 0.0f);
#pragma unroll
      for (int k = 0; k < 16; k++) acc = cfma(rp[k*9 + l], e[k], acc);
      unsigned short rh, rl, ih, il;
      split_bf(acc.x, rh, rl); split_bf(acc.y, ih, il);
      AH[i*9 + l] = (unsigned int)rh | ((unsigned int)ih << 16);
      AL[i*9 + l] = (unsigned int)rl | ((unsigned int)il << 16);
    }
  }
}

// GEMM: per o: C[2048][256] += Re(A*B^T) with split-bf16 3-product schedule, K'=54 chunks of 32.
// A buffer: A_hi at offset 0, A_lo at ALO_H halves. B rows: 1152 halves [hi|lo].
#define ALO_H 37748736u
__global__ __launch_bounds__(256) void k_x2m(const unsigned short* __restrict__ A,
                                             const unsigned short* __restrict__ B,
                                             float* __restrict__ out){
  __shared__ __align__(16) unsigned short At[128*32];
  __shared__ __align__(16) unsigned short Bt[128*32];
  int t = threadIdx.x;
  int j = blockIdx.x;                   // 1024
  int orig = (j & 7) * 128 + (j >> 3);  // same-o blocks grouped per XCD
  int o  = orig >> 5;
  int mb = (orig >> 1) & 15;
  int nb = orig & 1;
  const unsigned short* Ab = A + ((size_t)o*2048 + mb*128 + (t>>2))*576 + (t&3)*8;
  const unsigned short* Bb = B + ((size_t)o*256  + nb*128 + (t>>2))*1152 + (t&3)*8;
  int ln = t & 63;
  int wm = t >> 7, wn = (t >> 6) & 1;
  int lrow = ln & 15, lk = (ln >> 4) * 8;
  f32x4 acc[4][4];
#pragma unroll
  for (int mi = 0; mi < 4; mi++)
#pragma unroll
    for (int ni = 0; ni < 4; ni++) acc[mi][ni] = (f32x4){0.f,0.f,0.f,0.f};

  for (int ks = 0; ks < 54; ks++){
    int kA = ks % 18;                     // A chunk (hi for ks<36, lo after)
    int kB = ks % 36;                     // B' chunk (hi 0-17, lo 18-35)
    const unsigned short* Ap = Ab + (ks >= 36 ? (size_t)ALO_H : 0) + (size_t)kA*32;
    __syncthreads();
    GLOAD16(At + (size_t)t*8,        Ap);
    GLOAD16(At + 2048 + (size_t)t*8, Ap + (size_t)64*576);
    GLOAD16(Bt + (size_t)t*8,        Bb + (size_t)kB*32);
    GLOAD16(Bt + 2048 + (size_t)t*8, Bb + (size_t)kB*32 + (size_t)64*1152);
    __syncthreads();
    bf16x8 av[4], bv[4];
#pragma unroll
    for (int mi = 0; mi < 4; mi++)
      av[mi] = *(const bf16x8*)(At + (wm*64 + mi*16 + lrow)*32 + lk);
#pragma unroll
    for (int ni = 0; ni < 4; ni++)
      bv[ni] = *(const bf16x8*)(Bt + (wn*64 + ni*16 + lrow)*32 + lk);
#pragma unroll
    for (int mi = 0; mi < 4; mi++)
#pragma unroll
      for (int ni = 0; ni < 4; ni++)
        acc[mi][ni] = __builtin_amdgcn_mfma_f32_16x16x32_bf16(av[mi], bv[ni], acc[mi][ni], 0, 0, 0);
  }
  // epilogue: C/D layout col=lane&15, row=(lane>>4)*4+reg  [m89-verified]
  int nglob = nb*128 + wn*64 + (ln & 15);
#pragma unroll
  for (int mi = 0; mi < 4; mi++){
#pragma unroll
    for (int r = 0; r < 4; r++){
      int m = mb*128 + wm*64 + mi*16 + (ln >> 4)*4 + r;
      int b = m >> 8, z = m & 255;
      float* op = out + (((size_t)(b*32 + o) * 256 + z) * 256) + nglob;
#pragma unroll
      for (int ni = 0; ni < 4; ni++)
        op[ni*16] += acc[mi][ni][r];
    }
  }
}

extern "C" void kernel_launch(void* const* d_in, const int* in_sizes, int n_in,
                              void* d_out, int out_size, void* d_ws, size_t ws_size,
                              hipStream_t stream){
  const float* x    = (const float*)d_in[0];
  const float* rr   = (const float*)d_in[1];
  const float* ri   = (const float*)d_in[2];
  const float* p1r  = (const float*)d_in[3];
  const float* p1i  = (const float*)d_in[4];
  const float* p2r  = (const float*)d_in[5];
  const float* p2i  = (const float*)d_in[6];
  const float* bias = (const float*)d_in[7];
  float* out = (float*)d_out;

  char* ws = (char*)d_ws;
  size_t off = 0;
  c32* alpha = (c32*)(ws + off); off += (size_t)NB * CIn * NYF * NN1 * sizeof(c32);   // 67.6 MB
  c32* r1b   = (c32*)(ws + off); off += (size_t)NB * COut * NYF * NN1 * sizeof(c32);  // 67.6 MB
  c32* P1    = (c32*)(ws + off); off += (size_t)NIO * NK1 * NN1 * sizeof(c32);        // 33.6 MB
  c32* P2b   = (c32*)(ws + off); off += (size_t)NIO * NK2 * NYF * sizeof(c32);        //  9.5 MB
  c32* R2b   = (c32*)(ws + off); off += (size_t)NIO * NK1 * NYF * sizeof(c32);        // 16.9 MB
  c32* E1b   = (c32*)(ws + off); off += (size_t)NIO * NK1 * NN1 * sizeof(c32);        // 33.6 MB
  c32* r2b   = (c32*)(ws + off); off += (size_t)NB * NIO * NKL * sizeof(c32);         //  9.4 MB
  float2* tw = (float2*)(ws + off); off += 256 * sizeof(float2);
  // x2 GEMM operands alias the dead alpha..R2b pool (195 MB), used only after k_inv_y/k_r2k:
  // A_hi 75.5MB @0, A_lo 75.5MB @75.5MB, B' 18.9MB @151MB  -> ends at 170MB < 195MB
  unsigned short* Abf  = (unsigned short*)(ws + 0);
  unsigned short* E2bf = (unsigned short*)(ws + 150994944);

  k_tw<<<1, 256, 0, stream>>>(tw);
  k_p1<<<NIO * NK1, 256, 0, stream>>>(p1r, p1i, P1);
  k_p2<<<(NIO * NK2 * NYF + 255) / 256, 256, 0, stream>>>(p2r, p2i, P2b);
  k_e1<<<NIO * NK1, 256, 0, stream>>>(p1r, p1i, E1b);
  k_R2<<<(NIO * NK1 * NYF + 255) / 256, 256, 0, stream>>>(rr, ri, P2b, R2b);

  k_fwd_y<<<NB * CIn * 8, 256, 0, stream>>>(x, tw, alpha);
  k_fft_x<0><<<NB * CIn * NYF / 16, 256, 0, stream>>>(tw, alpha);

  k_r1<<<COut * NYF, 256, 0, stream>>>(alpha, P1, R2b, r1b);
  k_r2k<<<NB * CIn * COut, 256, 0, stream>>>(alpha, P1, P2b, rr, ri, r2b);

  k_fft_x<1><<<NB * COut * NYF / 16, 256, 0, stream>>>(tw, r1b);
  k_inv_y<<<NB * COut * 8, 256, 0, stream>>>(r1b, bias, tw, out);

  // alpha..R2b now dead -> safe to overwrite with GEMM operands
  k_e2b<<<32, 256, 0, stream>>>(p2r, p2i, (unsigned int*)E2bf);
  k_v<<<256, 256, 0, stream>>>(r2b, E1b, (unsigned int*)Abf, (unsigned int*)(Abf + ALO_H));
  k_x2m<<<1024, 256, 0, stream>>>(Abf, E2bf, out);
}

// Round 6
// 1609.172 us; speedup vs baseline: 1.2229x; 1.0032x over previous
//
#include <hip/hip_runtime.h>
#include <math.h>

#define NB 8
#define CIn 32
#define COut 32
#define NIO 1024      // CIn*CO
#define NN1 256
#define NN2 256
#define NYF 129       // NN2/2+1
#define NK1 16
#define NK2 9
#define NKL 144       // NK1*NK2

typedef float2 c32;
typedef __attribute__((ext_vector_type(8))) __bf16 bf16x8;
typedef __attribute__((ext_vector_type(4))) float f32x4;

__device__ __forceinline__ c32 cadd(c32 a, c32 b){ return make_float2(a.x+b.x, a.y+b.y); }
__device__ __forceinline__ c32 csub(c32 a, c32 b){ return make_float2(a.x-b.x, a.y-b.y); }
__device__ __forceinline__ c32 cmul(c32 a, c32 b){ return make_float2(a.x*b.x - a.y*b.y, a.x*b.y + a.y*b.x); }
__device__ __forceinline__ c32 cfma(c32 a, c32 b, c32 acc){
  acc.x = fmaf(a.x, b.x, acc.x); acc.x = fmaf(-a.y, b.y, acc.x);
  acc.y = fmaf(a.x, b.y, acc.y); acc.y = fmaf(a.y, b.x, acc.y);
  return acc;
}
__device__ __forceinline__ unsigned short f2bf(float f){
  unsigned int u = __float_as_uint(f);
  u += 0x7FFF + ((u >> 16) & 1);
  return (unsigned short)(u >> 16);
}
__device__ __forceinline__ float bf2f(unsigned short h){
  unsigned int u = ((unsigned int)h) << 16;
  return __uint_as_float(u);
}
__device__ __forceinline__ void split_bf(float f, unsigned short& hi, unsigned short& lo){
  hi = f2bf(f);
  lo = f2bf(f - bf2f(hi));
}

#define GLOAD16(lptr, gptr) \
  __builtin_amdgcn_global_load_lds((const __attribute__((address_space(1))) unsigned int*)(gptr), \
                                   (__attribute__((address_space(3))) unsigned int*)(lptr), 16, 0, 0)

// ---------------- FFT-256 via four-step radix-16 ----------------
template<int INV> __device__ __forceinline__ c32 rot90(c32 a){
  return INV ? make_float2(-a.y, a.x) : make_float2(a.y, -a.x);
}
template<int INV> __device__ __forceinline__ void dft4(c32& a0, c32& a1, c32& a2, c32& a3){
  c32 t0 = cadd(a0,a2), t1 = csub(a0,a2);
  c32 t2 = cadd(a1,a3), t3 = rot90<INV>(csub(a1,a3));
  a0 = cadd(t0,t2); a1 = cadd(t1,t3); a2 = csub(t0,t2); a3 = csub(t1,t3);
}
__device__ __forceinline__ int SLOT16(int k){ return 4*(k&3) + (k>>2); }
template<int INV> __device__ __forceinline__ c32 twg(const float2* ltw, int idx){
  float2 w = ltw[idx & 255];
  return INV ? make_float2(w.x, w.y) : make_float2(w.x, -w.y);
}
template<int INV> __device__ __forceinline__ void fft16r(c32 v[16], const float2* ltw){
#pragma unroll
  for (int bp = 0; bp < 4; bp++) dft4<INV>(v[bp], v[4+bp], v[8+bp], v[12+bp]);
#pragma unroll
  for (int c = 1; c < 4; c++)
#pragma unroll
    for (int bp = 1; bp < 4; bp++)
      v[4*c+bp] = cmul(v[4*c+bp], twg<INV>(ltw, 16*bp*c));
#pragma unroll
  for (int c = 0; c < 4; c++) dft4<INV>(v[4*c], v[4*c+1], v[4*c+2], v[4*c+3]);
}
template<int INV>
__device__ __forceinline__ void fft256_core(c32 v[16], int b, c32* tile, const float2* ltw){
  fft16r<INV>(v, ltw);
#pragma unroll
  for (int c = 0; c < 16; c++){
    c32 g = (c && b) ? cmul(v[SLOT16(c)], twg<INV>(ltw, b*c)) : v[SLOT16(c)];
    tile[c*17 + b] = g;
  }
  __syncthreads();
#pragma unroll
  for (int j = 0; j < 16; j++) v[j] = tile[b*17 + j];
  fft16r<INV>(v, ltw);
}

// ---------- precompute tables ----------
__global__ void k_tw(float2* __restrict__ tw){
  int m = threadIdx.x;
  double ang = 6.283185307179586 * (double)m / 256.0;
  tw[m] = make_float2((float)cos(ang), (float)sin(ang));
}

__global__ void k_p2(const float* __restrict__ p2r, const float* __restrict__ p2i, c32* __restrict__ P2){
  int idx = blockIdx.x * 256 + threadIdx.x;
  if (idx >= NIO * NK2 * NYF) return;
  int y = idx % NYF; int iol = idx / NYF;
  float a = -p2r[iol];
  float b = 6.2831853071795864f * (float)y - p2i[iol];
  float inv = 1.0f / fmaf(a, a, b * b);
  P2[idx] = make_float2(a * inv, -b * inv);
}

__global__ void k_e1(const float* __restrict__ p1r, const float* __restrict__ p1i, c32* __restrict__ E1){
  int idx = blockIdx.x * 256 + threadIdx.x;
  int z = idx & 255; int iok = idx >> 8;
  float t = (float)z * (1.0f / 256.0f);
  float er = expf(p1r[iok] * t);
  float s, c; sincosf(p1i[iok] * t, &s, &c);
  E1[idx] = make_float2(er * c, er * s);
}

// ---------- forward: rfft along n2 (paired rows), write alpha[(bi*129+y)*256+n1], scaled 1/65536 ----------
__global__ __launch_bounds__(256) void k_fwd_y(const float* __restrict__ x, const float2* __restrict__ tw,
                                               c32* __restrict__ alpha){
  __shared__ c32 tile[16*272];
  __shared__ float2 ltw[256];
  int t = threadIdx.x;
  ltw[t] = tw[t];
  int bi = blockIdx.x >> 3;
  int n1c = (blockIdx.x & 7) << 5;
  int row = t >> 4, b = t & 15;
  const float* xe = x + ((size_t)bi * 256 + n1c + 2 * row) * 256;
  c32 v[16];
#pragma unroll
  for (int a = 0; a < 16; a++)
    v[a] = make_float2(xe[16*a + b], xe[256 + 16*a + b]);
  __syncthreads();
  fft256_core<0>(v, b, tile + row*272, ltw);
  __syncthreads();
#pragma unroll
  for (int d = 0; d < 16; d++)
    tile[row*272 + b + 16*d] = v[SLOT16(d)];
  __syncthreads();
  const float sc = 0.5f / 65536.0f;
#pragma unroll
  for (int j = 0; j < 8; j++){
    int item = t + 256*j;
    int h = item & 127, r2 = item >> 7;
    c32* Zb = tile + r2*272;
    if (h == 0){
      c32 z0 = Zb[0], z1 = Zb[128];
      Zb[0]   = make_float2(z0.x * (2.0f*sc), z0.y * (2.0f*sc));
      Zb[128] = make_float2(z1.x * (2.0f*sc), z1.y * (2.0f*sc));
    } else {
      c32 zk = Zb[h], zm = Zb[256 - h];
      c32 A = make_float2(sc*(zk.x + zm.x), sc*(zk.y - zm.y));
      c32 B = make_float2(sc*(zk.y + zm.y), sc*(zm.x - zk.x));
      Zb[h] = A; Zb[256 - h] = B;
    }
  }
  __syncthreads();
  for (int j = 0; j < 17; j++){
    int idx = t + 256*j;
    if (idx >= 129*32) break;
    int y = idx >> 5, n1i = idx & 31;
    c32* Zb = tile + (n1i >> 1)*272;
    c32 val;
    if ((n1i & 1) == 0)
      val = (y == 0) ? make_float2(Zb[0].x, 0.0f)
          : (y == 128) ? make_float2(Zb[128].x, 0.0f) : Zb[y];
    else
      val = (y == 0) ? make_float2(Zb[0].y, 0.0f)
          : (y == 128) ? make_float2(Zb[128].y, 0.0f) : Zb[256 - y];
    alpha[((size_t)bi * 129 + y) * 256 + n1c + n1i] = val;
  }
}

// ---------- complex FFT-256 on contiguous rows, in place ----------
template<int INV>
__global__ __launch_bounds__(256) void k_fft_x(const float2* __restrict__ tw, c32* __restrict__ buf){
  __shared__ c32 tile[16*272];
  __shared__ float2 ltw[256];
  int t = threadIdx.x;
  ltw[t] = tw[t];
  int row = t >> 4, b = t & 15;
  c32* p = buf + ((size_t)blockIdx.x * 16 + row) * 256;
  c32 v[16];
#pragma unroll
  for (int a = 0; a < 16; a++) v[a] = p[16*a + b];
  __syncthreads();
  fft256_core<INV>(v, b, tile + row*272, ltw);
#pragma unroll
  for (int d = 0; d < 16; d++) p[b + 16*d] = v[SLOT16(d)];
}

// ---------- inverse rfft along y (paired z-columns) + bias, writes out ----------
__global__ __launch_bounds__(256) void k_inv_y(const c32* __restrict__ r1, const float* __restrict__ bias,
                                               const float2* __restrict__ tw, float* __restrict__ out){
  __shared__ c32 tile[16*272];
  __shared__ float2 ltw[256];
  c32* SA = tile;
  int t = threadIdx.x;
  ltw[t] = tw[t];
  int bo = blockIdx.x >> 3;
  int z0 = (blockIdx.x & 7) << 5;
  for (int j = 0; j < 17; j++){
    int idx = t + 256*j;
    if (idx >= 129*32) break;
    int y = idx >> 5, zi = idx & 31;
    SA[y*33 + zi] = r1[((size_t)bo * 129 + y) * 256 + z0 + zi];
  }
  __syncthreads();
  int p = t >> 4, b = t & 15;
  c32 v[16];
#pragma unroll
  for (int a = 0; a < 16; a++){
    int k = 16*a + b;
    int m = (k <= 128) ? k : 256 - k;
    c32 A = SA[m*33 + 2*p], B = SA[m*33 + 2*p + 1];
    if (k == 0 || k == 128)  v[a] = make_float2(A.x, B.x);
    else if (k < 128)        v[a] = make_float2(A.x - B.y, A.y + B.x);
    else                     v[a] = make_float2(A.x + B.y, B.x - A.y);
  }
  __syncthreads();
  fft256_core<1>(v, b, tile + p*272, ltw);
  float bv = bias[bo & 31];
  float* o0 = out + ((size_t)bo * 256 + z0 + 2*p) * 256;
#pragma unroll
  for (int d = 0; d < 16; d++){
    c32 zz = v[SLOT16(d)];
    o0[b + 16*d]       = zz.x + bv;
    o0[256 + b + 16*d] = zz.y + bv;
  }
}

// ---------- mode mixing r1: poles on-the-fly, R2 staged in LDS, 4-y tile ----------
// block: (o, y4-tile). grid 1056 = 8 XCD chunks * 132 (y-major within chunk -> same-y blocks co-XCD).
__global__ __launch_bounds__(256, 4) void k_r1(const c32* __restrict__ alpha,
                                               const float* __restrict__ rr, const float* __restrict__ ri,
                                               const float* __restrict__ p1r, const float* __restrict__ p1i,
                                               const c32* __restrict__ P2,
                                               c32* __restrict__ r1){
  __shared__ float4 R2r4[512], R2i4[512];    // [i*16+k] -> 4 y's
  int t = threadIdx.x;
  int j = blockIdx.x;
  int g = (j & 7) * 132 + (j >> 3);          // XCD-chunked
  int y4 = g >> 5, o = g & 31;               // y4: 0..32
  int y0 = y4 * 4;
  int yv = (y0 + 4 <= 129) ? 4 : (129 - y0);
  // build R2[i][k][yy] = sum_l res[io,k,l] * P2[io,l,y0+yy]
  float* R2r = (float*)R2r4; float* R2i = (float*)R2i4;
#pragma unroll
  for (int e = 0; e < 8; e++){
    int flat = t + e * 256;                  // i*64 + k*4 + yy
    int i = flat >> 6, k = (flat >> 2) & 15, yy = flat & 3;
    int io = i * 32 + o;
    int iok = io * 16 + k;
    int ya = y0 + yy; if (ya > 128) ya = 128;
    float ar = 0.f, ai = 0.f;
#pragma unroll
    for (int l = 0; l < 9; l++){
      float rsr = rr[iok*9 + l], rsi = ri[iok*9 + l];
      c32 p2 = P2[((size_t)io*9 + l)*129 + ya];
      ar = fmaf(rsr, p2.x, ar); ar = fmaf(-rsi, p2.y, ar);
      ai = fmaf(rsr, p2.y, ai); ai = fmaf(rsi, p2.x, ai);
    }
    R2r[flat] = ar; R2i[flat] = ai;
  }
  __syncthreads();
  int x = t;
  float fx = (x < 128) ? (float)x : (float)(x - 256);
  float lamb = 6.2831853071795864f * fx;
  float acr[8][4], aci[8][4];
#pragma unroll
  for (int b = 0; b < 8; b++)
#pragma unroll
    for (int yy = 0; yy < 4; yy++){ acr[b][yy] = 0.f; aci[b][yy] = 0.f; }
  size_t yoff[4];
#pragma unroll
  for (int yy = 0; yy < 4; yy++){
    int ya = y0 + yy; if (ya > 128) ya = 128;
    yoff[yy] = (size_t)ya * 256;
  }
  for (int i = 0; i < 32; i++){
    int io = i * 32 + o;
    const float* pr = p1r + io * 16;
    const float* pim = p1i + io * 16;
    float hwr[4] = {0.f,0.f,0.f,0.f}, hwi[4] = {0.f,0.f,0.f,0.f};
#pragma unroll
    for (int k = 0; k < 16; k++){
      float a = -pr[k];
      float b = lamb - pim[k];
      float inv = 1.0f / fmaf(a, a, b * b);
      float px = a * inv, py = -b * inv;
      float4 r4 = R2r4[i*16 + k], i4 = R2i4[i*16 + k];
      hwr[0]=fmaf(px,r4.x,hwr[0]); hwr[0]=fmaf(-py,i4.x,hwr[0]);
      hwi[0]=fmaf(px,i4.x,hwi[0]); hwi[0]=fmaf( py,r4.x,hwi[0]);
      hwr[1]=fmaf(px,r4.y,hwr[1]); hwr[1]=fmaf(-py,i4.y,hwr[1]);
      hwi[1]=fmaf(px,i4.y,hwi[1]); hwi[1]=fmaf( py,r4.y,hwi[1]);
      hwr[2]=fmaf(px,r4.z,hwr[2]); hwr[2]=fmaf(-py,i4.z,hwr[2]);
      hwi[2]=fmaf(px,i4.z,hwi[2]); hwi[2]=fmaf( py,r4.z,hwi[2]);
      hwr[3]=fmaf(px,r4.w,hwr[3]); hwr[3]=fmaf(-py,i4.w,hwr[3]);
      hwi[3]=fmaf(px,i4.w,hwi[3]); hwi[3]=fmaf( py,r4.w,hwi[3]);
    }
    const c32* ab = alpha + (size_t)i * 129 * 256 + x;
#pragma unroll
    for (int b = 0; b < 8; b++){
      const c32* ap = ab + (size_t)b * 32 * 129 * 256;
#pragma unroll
      for (int yy = 0; yy < 4; yy++){
        c32 av = ap[yoff[yy]];
        acr[b][yy]=fmaf(av.x,hwr[yy],acr[b][yy]); acr[b][yy]=fmaf(-av.y,hwi[yy],acr[b][yy]);
        aci[b][yy]=fmaf(av.x,hwi[yy],aci[b][yy]); aci[b][yy]=fmaf( av.y,hwr[yy],aci[b][yy]);
      }
    }
  }
#pragma unroll
  for (int b = 0; b < 8; b++)
    for (int yy = 0; yy < yv; yy++)
      r1[(((size_t)(b*32 + o) * 129) + y0 + yy) * 256 + x] = make_float2(acr[b][yy], aci[b][yy]);
}

// ---------- r2[b,io,k,l]: P1 on-the-fly ----------
__global__ __launch_bounds__(256) void k_r2k(const c32* __restrict__ alpha,
                                             const float* __restrict__ p1r, const float* __restrict__ p1i,
                                             const c32* __restrict__ P2,
                                             const float* __restrict__ rr, const float* __restrict__ ri,
                                             c32* __restrict__ r2){
  __shared__ float Tr[NK2][257], Ti[NK2][257];
  __shared__ float P2r[NK2][NYF], P2i[NK2][NYF];
  int t = threadIdx.x;
  int bid = blockIdx.x;             // (b*CI+i)*CO + o
  int o = bid & 31; int bi = bid >> 5;
  int i = bi & 31;  int b = bi >> 5;
  int io = i * COut + o;
  for (int s = t; s < NK2 * NYF; s += 256){
    c32 v = P2[(size_t)io * NK2 * NYF + s];
    int l = s / NYF, y = s - l * NYF;
    P2r[l][y] = v.x; P2i[l][y] = v.y;
  }
  __syncthreads();
  {
    float tr[NK2], ti[NK2];
#pragma unroll
    for (int l = 0; l < NK2; l++){ tr[l] = 0.0f; ti[l] = 0.0f; }
    const c32* ap = alpha + (size_t)bi * NYF * 256 + t;
    for (int y = 0; y < NYF; y++){
      c32 a = ap[(size_t)y * 256];
#pragma unroll
      for (int l = 0; l < NK2; l++){
        float c = P2r[l][y], s2 = P2i[l][y];
        tr[l] = fmaf(a.x, c, tr[l]); tr[l] = fmaf(-a.y, s2, tr[l]);
        ti[l] = fmaf(a.x, s2, ti[l]); ti[l] = fmaf(a.y, c, ti[l]);
      }
    }
#pragma unroll
    for (int l = 0; l < NK2; l++){ Tr[l][t] = tr[l]; Ti[l][t] = ti[l]; }
  }
  __syncthreads();
  if (t < NKL){
    int k = t / NK2, l = t - k * NK2;
    float pa = -p1r[io*16 + k];
    float pb = p1i[io*16 + k];
    float gr = 0.0f, gi = 0.0f;
#pragma unroll 4
    for (int xx = 0; xx < 256; xx++){
      float fx = (xx < 128) ? (float)xx : (float)(xx - 256);
      float bb = 6.2831853071795864f * fx - pb;
      float inv = 1.0f / fmaf(pa, pa, bb * bb);
      float px = pa * inv, py = -bb * inv;
      float trv = Tr[l][xx], tiv = Ti[l][xx];
      gr = fmaf(px, trv, gr); gr = fmaf(-py, tiv, gr);
      gi = fmaf(px, tiv, gi); gi = fmaf( py, trv, gi);
    }
    float resr = rr[((size_t)io * NK1 + k) * NK2 + l];
    float resi = ri[((size_t)io * NK1 + k) * NK2 + l];
    float outr = -(resr * gr - resi * gi);
    float outi = -(resr * gi + resi * gr);
    r2[((size_t)b * NIO + io) * NKL + t] = make_float2(outr, outi);
  }
}

// ---------- x2 path: split-bf16 MFMA GEMM pipeline ----------
__global__ __launch_bounds__(256) void k_e2b(const float* __restrict__ p2r, const float* __restrict__ p2i,
                                             unsigned int* __restrict__ B){
  int o = blockIdx.x, w = threadIdx.x;
  float tt = (float)w * (1.0f / 256.0f);
  unsigned int* brow = B + ((size_t)o * 256 + w) * 576;   // 576 uints = 1152 halves
  for (int i = 0; i < 32; i++){
    int io = i * 32 + o;
#pragma unroll
    for (int l = 0; l < 9; l++){
      float pr = p2r[io*9 + l], pi = p2i[io*9 + l];
      float er = expf(pr * tt);
      float s, c; sincosf(pi * tt, &s, &c);
      float vr = er * c, vi = -er * s;
      unsigned short rh, rl, ih, il;
      split_bf(vr, rh, rl); split_bf(vi, ih, il);
      brow[i*9 + l]       = (unsigned int)rh | ((unsigned int)ih << 16);
      brow[288 + i*9 + l] = (unsigned int)rl | ((unsigned int)il << 16);
    }
  }
}

__global__ __launch_bounds__(256) void k_v(const c32* __restrict__ r2, const c32* __restrict__ E1,
                                           unsigned int* __restrict__ Ahi, unsigned int* __restrict__ Alo){
  int t = threadIdx.x;                 // z
  int j = blockIdx.x;                  // 256 = 8 xcd * 32
  int o = (j & 7) * 4 + ((j >> 3) & 3);
  int b = j >> 5;
  size_t rowoff = ((size_t)o * 2048 + b * 256 + t) * 288;
  unsigned int* AH = Ahi + rowoff;
  unsigned int* AL = Alo + rowoff;
  for (int i = 0; i < 32; i++){
    int io = i * 32 + o;
    const c32* e1p = E1 + (size_t)io * 16 * 256 + t;
    c32 e[16];
#pragma unroll
    for (int k = 0; k < 16; k++) e[k] = e1p[(size_t)k * 256];
    const c32* rp = r2 + ((size_t)b * NIO + io) * NKL;
#pragma unroll
    for (int l = 0; l < 9; l++){
      c32 acc = make_float2(0.0f, 0.0f);
#pragma unroll
      for (int k = 0; k < 16; k++) acc = cfma(rp[k*9 + l], e[k], acc);
      unsigned short rh, rl, ih, il;
      split_bf(acc.x, rh, rl); split_bf(acc.y, ih, il);
      AH[i*9 + l] = (unsigned int)rh | ((unsigned int)ih << 16);
      AL[i*9 + l] = (unsigned int)rl | ((unsigned int)il << 16);
    }
  }
}

// GEMM: per o: C[2048][256] += Re(A*B^T), split-bf16 3-product schedule, 54 K-chunks of 32.
#define ALO_H 37748736u
__global__ __launch_bounds__(256) void k_x2m(const unsigned short* __restrict__ A,
                                             const unsigned short* __restrict__ B,
                                             float* __restrict__ out){
  __shared__ __align__(16) unsigned short At[128*32];
  __shared__ __align__(16) unsigned short Bt[128*32];
  int t = threadIdx.x;
  int j = blockIdx.x;                   // 1024
  int orig = (j & 7) * 128 + (j >> 3);  // same-o blocks grouped per XCD
  int o  = orig >> 5;
  int mb = (orig >> 1) & 15;
  int nb = orig & 1;
  const unsigned short* Ab = A + ((size_t)o*2048 + mb*128 + (t>>2))*576 + (t&3)*8;
  const unsigned short* Bb = B + ((size_t)o*256  + nb*128 + (t>>2))*1152 + (t&3)*8;
  int ln = t & 63;
  int wm = t >> 7, wn = (t >> 6) & 1;
  int lrow = ln & 15, lk = (ln >> 4) * 8;
  f32x4 acc[4][4];
#pragma unroll
  for (int mi = 0; mi < 4; mi++)
#pragma unroll
    for (int ni = 0; ni < 4; ni++) acc[mi][ni] = (f32x4){0.f,0.f,0.f,0.f};

  for (int ks = 0; ks < 54; ks++){
    int kA = ks % 18;
    int kB = ks % 36;
    const unsigned short* Ap = Ab + (ks >= 36 ? (size_t)ALO_H : 0) + (size_t)kA*32;
    __syncthreads();
    GLOAD16(At + (size_t)t*8,        Ap);
    GLOAD16(At + 2048 + (size_t)t*8, Ap + (size_t)64*576);
    GLOAD16(Bt + (size_t)t*8,        Bb + (size_t)kB*32);
    GLOAD16(Bt + 2048 + (size_t)t*8, Bb + (size_t)kB*32 + (size_t)64*1152);
    __syncthreads();
    bf16x8 av[4], bv[4];
#pragma unroll
    for (int mi = 0; mi < 4; mi++)
      av[mi] = *(const bf16x8*)(At + (wm*64 + mi*16 + lrow)*32 + lk);
#pragma unroll
    for (int ni = 0; ni < 4; ni++)
      bv[ni] = *(const bf16x8*)(Bt + (wn*64 + ni*16 + lrow)*32 + lk);
#pragma unroll
    for (int mi = 0; mi < 4; mi++)
#pragma unroll
      for (int ni = 0; ni < 4; ni++)
        acc[mi][ni] = __builtin_amdgcn_mfma_f32_16x16x32_bf16(av[mi], bv[ni], acc[mi][ni], 0, 0, 0);
  }
  int nglob = nb*128 + wn*64 + (ln & 15);
#pragma unroll
  for (int mi = 0; mi < 4; mi++){
#pragma unroll
    for (int r = 0; r < 4; r++){
      int m = mb*128 + wm*64 + mi*16 + (ln >> 4)*4 + r;
      int b = m >> 8, z = m & 255;
      float* op = out + (((size_t)(b*32 + o) * 256 + z) * 256) + nglob;
#pragma unroll
      for (int ni = 0; ni < 4; ni++)
        op[ni*16] += acc[mi][ni][r];
    }
  }
}

extern "C" void kernel_launch(void* const* d_in, const int* in_sizes, int n_in,
                              void* d_out, int out_size, void* d_ws, size_t ws_size,
                              hipStream_t stream){
  const float* x    = (const float*)d_in[0];
  const float* rr   = (const float*)d_in[1];
  const float* ri   = (const float*)d_in[2];
  const float* p1r  = (const float*)d_in[3];
  const float* p1i  = (const float*)d_in[4];
  const float* p2r  = (const float*)d_in[5];
  const float* p2i  = (const float*)d_in[6];
  const float* bias = (const float*)d_in[7];
  float* out = (float*)d_out;

  // ws layout kept byte-identical to round 5 (P1/R2b now unused holes; aliasing proven safe)
  char* ws = (char*)d_ws;
  size_t off = 0;
  c32* alpha = (c32*)(ws + off); off += (size_t)NB * CIn * NYF * NN1 * sizeof(c32);   // 67.6 MB
  c32* r1b   = (c32*)(ws + off); off += (size_t)NB * COut * NYF * NN1 * sizeof(c32);  // 67.6 MB
  off += (size_t)NIO * NK1 * NN1 * sizeof(c32);                                       // (hole: old P1)
  c32* P2b   = (c32*)(ws + off); off += (size_t)NIO * NK2 * NYF * sizeof(c32);        //  9.5 MB
  off += (size_t)NIO * NK1 * NYF * sizeof(c32);                                       // (hole: old R2b)
  c32* E1b   = (c32*)(ws + off); off += (size_t)NIO * NK1 * NN1 * sizeof(c32);        // 33.6 MB
  c32* r2b   = (c32*)(ws + off); off += (size_t)NB * NIO * NKL * sizeof(c32);         //  9.4 MB
  float2* tw = (float2*)(ws + off); off += 256 * sizeof(float2);
  unsigned short* Abf  = (unsigned short*)(ws + 0);
  unsigned short* E2bf = (unsigned short*)(ws + 150994944);

  k_tw<<<1, 256, 0, stream>>>(tw);
  k_p2<<<(NIO * NK2 * NYF + 255) / 256, 256, 0, stream>>>(p2r, p2i, P2b);
  k_e1<<<NIO * NK1, 256, 0, stream>>>(p1r, p1i, E1b);

  k_fwd_y<<<NB * CIn * 8, 256, 0, stream>>>(x, tw, alpha);
  k_fft_x<0><<<NB * CIn * NYF / 16, 256, 0, stream>>>(tw, alpha);

  k_r1<<<1056, 256, 0, stream>>>(alpha, rr, ri, p1r, p1i, P2b, r1b);
  k_r2k<<<NB * CIn * COut, 256, 0, stream>>>(alpha, p1r, p1i, P2b, rr, ri, r2b);

  k_fft_x<1><<<NB * COut * NYF / 16, 256, 0, stream>>>(tw, r1b);
  k_inv_y<<<NB * COut * 8, 256, 0, stream>>>(r1b, bias, tw, out);

  k_e2b<<<32, 256, 0, stream>>>(p2r, p2i, (unsigned int*)E2bf);
  k_v<<<256, 256, 0, stream>>>(r2b, E1b, (unsigned int*)Abf, (unsigned int*)(Abf + ALO_H));
  k_x2m<<<1024, 256, 0, stream>>>(Abf, E2bf, out);
}

// Round 7
// 1398.533 us; speedup vs baseline: 1.4071x; 1.1506x over previous
//
#include <hip/hip_runtime.h>
#include <math.h>

#define NB 8
#define CIn 32
#define COut 32
#define NIO 1024      // CIn*CO
#define NN1 256
#define NN2 256
#define NYF 129       // NN2/2+1
#define NK1 16
#define NK2 9
#define NKL 144       // NK1*NK2

typedef float2 c32;
typedef __attribute__((ext_vector_type(8))) __bf16 bf16x8;
typedef __attribute__((ext_vector_type(4))) float f32x4;

__device__ __forceinline__ c32 cadd(c32 a, c32 b){ return make_float2(a.x+b.x, a.y+b.y); }
__device__ __forceinline__ c32 csub(c32 a, c32 b){ return make_float2(a.x-b.x, a.y-b.y); }
__device__ __forceinline__ c32 cmul(c32 a, c32 b){ return make_float2(a.x*b.x - a.y*b.y, a.x*b.y + a.y*b.x); }
__device__ __forceinline__ c32 cfma(c32 a, c32 b, c32 acc){
  acc.x = fmaf(a.x, b.x, acc.x); acc.x = fmaf(-a.y, b.y, acc.x);
  acc.y = fmaf(a.x, b.y, acc.y); acc.y = fmaf(a.y, b.x, acc.y);
  return acc;
}
__device__ __forceinline__ unsigned short f2bf(float f){
  unsigned int u = __float_as_uint(f);
  u += 0x7FFF + ((u >> 16) & 1);
  return (unsigned short)(u >> 16);
}
__device__ __forceinline__ float bf2f(unsigned short h){
  unsigned int u = ((unsigned int)h) << 16;
  return __uint_as_float(u);
}
__device__ __forceinline__ void split_bf(float f, unsigned short& hi, unsigned short& lo){
  hi = f2bf(f);
  lo = f2bf(f - bf2f(hi));
}

#define GLOAD16(lptr, gptr) \
  __builtin_amdgcn_global_load_lds((const __attribute__((address_space(1))) unsigned int*)(gptr), \
                                   (__attribute__((address_space(3))) unsigned int*)(lptr), 16, 0, 0)

// ---------------- FFT-256 via four-step radix-16 ----------------
template<int INV> __device__ __forceinline__ c32 rot90(c32 a){
  return INV ? make_float2(-a.y, a.x) : make_float2(a.y, -a.x);
}
template<int INV> __device__ __forceinline__ void dft4(c32& a0, c32& a1, c32& a2, c32& a3){
  c32 t0 = cadd(a0,a2), t1 = csub(a0,a2);
  c32 t2 = cadd(a1,a3), t3 = rot90<INV>(csub(a1,a3));
  a0 = cadd(t0,t2); a1 = cadd(t1,t3); a2 = csub(t0,t2); a3 = csub(t1,t3);
}
__device__ __forceinline__ int SLOT16(int k){ return 4*(k&3) + (k>>2); }
template<int INV> __device__ __forceinline__ c32 twg(const float2* ltw, int idx){
  float2 w = ltw[idx & 255];
  return INV ? make_float2(w.x, w.y) : make_float2(w.x, -w.y);
}
template<int INV> __device__ __forceinline__ void fft16r(c32 v[16], const float2* ltw){
#pragma unroll
  for (int bp = 0; bp < 4; bp++) dft4<INV>(v[bp], v[4+bp], v[8+bp], v[12+bp]);
#pragma unroll
  for (int c = 1; c < 4; c++)
#pragma unroll
    for (int bp = 1; bp < 4; bp++)
      v[4*c+bp] = cmul(v[4*c+bp], twg<INV>(ltw, 16*bp*c));
#pragma unroll
  for (int c = 0; c < 4; c++) dft4<INV>(v[4*c], v[4*c+1], v[4*c+2], v[4*c+3]);
}
template<int INV>
__device__ __forceinline__ void fft256_core(c32 v[16], int b, c32* tile, const float2* ltw){
  fft16r<INV>(v, ltw);
#pragma unroll
  for (int c = 0; c < 16; c++){
    c32 g = (c && b) ? cmul(v[SLOT16(c)], twg<INV>(ltw, b*c)) : v[SLOT16(c)];
    tile[c*17 + b] = g;
  }
  __syncthreads();
#pragma unroll
  for (int j = 0; j < 16; j++) v[j] = tile[b*17 + j];
  fft16r<INV>(v, ltw);
}

// ---------- precompute tables ----------
__global__ void k_tw(float2* __restrict__ tw){
  int m = threadIdx.x;
  double ang = 6.283185307179586 * (double)m / 256.0;
  tw[m] = make_float2((float)cos(ang), (float)sin(ang));
}

__global__ void k_p2(const float* __restrict__ p2r, const float* __restrict__ p2i, c32* __restrict__ P2){
  int idx = blockIdx.x * 256 + threadIdx.x;
  if (idx >= NIO * NK2 * NYF) return;
  int y = idx % NYF; int iol = idx / NYF;
  float a = -p2r[iol];
  float b = 6.2831853071795864f * (float)y - p2i[iol];
  float inv = 1.0f / fmaf(a, a, b * b);
  P2[idx] = make_float2(a * inv, -b * inv);
}

__global__ void k_e1(const float* __restrict__ p1r, const float* __restrict__ p1i, c32* __restrict__ E1){
  int idx = blockIdx.x * 256 + threadIdx.x;
  int z = idx & 255; int iok = idx >> 8;
  float t = (float)z * (1.0f / 256.0f);
  float er = expf(p1r[iok] * t);
  float s, c; sincosf(p1i[iok] * t, &s, &c);
  E1[idx] = make_float2(er * c, er * s);
}

// ---------- forward: rfft along n2 (paired rows), write alpha[(bi*129+y)*256+n1], scaled 1/65536 ----------
__global__ __launch_bounds__(256) void k_fwd_y(const float* __restrict__ x, const float2* __restrict__ tw,
                                               c32* __restrict__ alpha){
  __shared__ c32 tile[16*272];
  __shared__ float2 ltw[256];
  int t = threadIdx.x;
  ltw[t] = tw[t];
  int bi = blockIdx.x >> 3;
  int n1c = (blockIdx.x & 7) << 5;
  int row = t >> 4, b = t & 15;
  const float* xe = x + ((size_t)bi * 256 + n1c + 2 * row) * 256;
  c32 v[16];
#pragma unroll
  for (int a = 0; a < 16; a++)
    v[a] = make_float2(xe[16*a + b], xe[256 + 16*a + b]);
  __syncthreads();
  fft256_core<0>(v, b, tile + row*272, ltw);
  __syncthreads();
#pragma unroll
  for (int d = 0; d < 16; d++)
    tile[row*272 + b + 16*d] = v[SLOT16(d)];
  __syncthreads();
  const float sc = 0.5f / 65536.0f;
#pragma unroll
  for (int j = 0; j < 8; j++){
    int item = t + 256*j;
    int h = item & 127, r2 = item >> 7;
    c32* Zb = tile + r2*272;
    if (h == 0){
      c32 z0 = Zb[0], z1 = Zb[128];
      Zb[0]   = make_float2(z0.x * (2.0f*sc), z0.y * (2.0f*sc));
      Zb[128] = make_float2(z1.x * (2.0f*sc), z1.y * (2.0f*sc));
    } else {
      c32 zk = Zb[h], zm = Zb[256 - h];
      c32 A = make_float2(sc*(zk.x + zm.x), sc*(zk.y - zm.y));
      c32 B = make_float2(sc*(zk.y + zm.y), sc*(zm.x - zk.x));
      Zb[h] = A; Zb[256 - h] = B;
    }
  }
  __syncthreads();
  for (int j = 0; j < 17; j++){
    int idx = t + 256*j;
    if (idx >= 129*32) break;
    int y = idx >> 5, n1i = idx & 31;
    c32* Zb = tile + (n1i >> 1)*272;
    c32 val;
    if ((n1i & 1) == 0)
      val = (y == 0) ? make_float2(Zb[0].x, 0.0f)
          : (y == 128) ? make_float2(Zb[128].x, 0.0f) : Zb[y];
    else
      val = (y == 0) ? make_float2(Zb[0].y, 0.0f)
          : (y == 128) ? make_float2(Zb[128].y, 0.0f) : Zb[256 - y];
    alpha[((size_t)bi * 129 + y) * 256 + n1c + n1i] = val;
  }
}

// ---------- complex FFT-256 on contiguous rows, in place ----------
template<int INV>
__global__ __launch_bounds__(256) void k_fft_x(const float2* __restrict__ tw, c32* __restrict__ buf){
  __shared__ c32 tile[16*272];
  __shared__ float2 ltw[256];
  int t = threadIdx.x;
  ltw[t] = tw[t];
  int row = t >> 4, b = t & 15;
  c32* p = buf + ((size_t)blockIdx.x * 16 + row) * 256;
  c32 v[16];
#pragma unroll
  for (int a = 0; a < 16; a++) v[a] = p[16*a + b];
  __syncthreads();
  fft256_core<INV>(v, b, tile + row*272, ltw);
#pragma unroll
  for (int d = 0; d < 16; d++) p[b + 16*d] = v[SLOT16(d)];
}

// ---------- inverse rfft along y (paired z-columns) + bias, writes out ----------
__global__ __launch_bounds__(256) void k_inv_y(const c32* __restrict__ r1, const float* __restrict__ bias,
                                               const float2* __restrict__ tw, float* __restrict__ out){
  __shared__ c32 tile[16*272];
  __shared__ float2 ltw[256];
  c32* SA = tile;
  int t = threadIdx.x;
  ltw[t] = tw[t];
  int bo = blockIdx.x >> 3;
  int z0 = (blockIdx.x & 7) << 5;
  for (int j = 0; j < 17; j++){
    int idx = t + 256*j;
    if (idx >= 129*32) break;
    int y = idx >> 5, zi = idx & 31;
    SA[y*33 + zi] = r1[((size_t)bo * 129 + y) * 256 + z0 + zi];
  }
  __syncthreads();
  int p = t >> 4, b = t & 15;
  c32 v[16];
#pragma unroll
  for (int a = 0; a < 16; a++){
    int k = 16*a + b;
    int m = (k <= 128) ? k : 256 - k;
    c32 A = SA[m*33 + 2*p], B = SA[m*33 + 2*p + 1];
    if (k == 0 || k == 128)  v[a] = make_float2(A.x, B.x);
    else if (k < 128)        v[a] = make_float2(A.x - B.y, A.y + B.x);
    else                     v[a] = make_float2(A.x + B.y, B.x - A.y);
  }
  __syncthreads();
  fft256_core<1>(v, b, tile + p*272, ltw);
  float bv = bias[bo & 31];
  float* o0 = out + ((size_t)bo * 256 + z0 + 2*p) * 256;
#pragma unroll
  for (int d = 0; d < 16; d++){
    c32 zz = v[SLOT16(d)];
    o0[b + 16*d]       = zz.x + bv;
    o0[256 + b + 16*d] = zz.y + bv;
  }
}

// ---------- mode mixing r1: poles on-the-fly, R2 staged in LDS, 4-y tile ----------
__global__ __launch_bounds__(256, 4) void k_r1(const c32* __restrict__ alpha,
                                               const float* __restrict__ rr, const float* __restrict__ ri,
                                               const float* __restrict__ p1r, const float* __restrict__ p1i,
                                               const c32* __restrict__ P2,
                                               c32* __restrict__ r1){
  __shared__ float4 R2r4[512], R2i4[512];    // [i*16+k] -> 4 y's
  int t = threadIdx.x;
  int j = blockIdx.x;
  int g = (j & 7) * 132 + (j >> 3);          // XCD-chunked
  int y4 = g >> 5, o = g & 31;               // y4: 0..32
  int y0 = y4 * 4;
  int yv = (y0 + 4 <= 129) ? 4 : (129 - y0);
  float* R2r = (float*)R2r4; float* R2i = (float*)R2i4;
#pragma unroll
  for (int e = 0; e < 8; e++){
    int flat = t + e * 256;                  // i*64 + k*4 + yy
    int i = flat >> 6, k = (flat >> 2) & 15, yy = flat & 3;
    int io = i * 32 + o;
    int iok = io * 16 + k;
    int ya = y0 + yy; if (ya > 128) ya = 128;
    float ar = 0.f, ai = 0.f;
#pragma unroll
    for (int l = 0; l < 9; l++){
      float rsr = rr[iok*9 + l], rsi = ri[iok*9 + l];
      c32 p2 = P2[((size_t)io*9 + l)*129 + ya];
      ar = fmaf(rsr, p2.x, ar); ar = fmaf(-rsi, p2.y, ar);
      ai = fmaf(rsr, p2.y, ai); ai = fmaf(rsi, p2.x, ai);
    }
    R2r[flat] = ar; R2i[flat] = ai;
  }
  __syncthreads();
  int x = t;
  float fx = (x < 128) ? (float)x : (float)(x - 256);
  float lamb = 6.2831853071795864f * fx;
  float acr[8][4], aci[8][4];
#pragma unroll
  for (int b = 0; b < 8; b++)
#pragma unroll
    for (int yy = 0; yy < 4; yy++){ acr[b][yy] = 0.f; aci[b][yy] = 0.f; }
  size_t yoff[4];
#pragma unroll
  for (int yy = 0; yy < 4; yy++){
    int ya = y0 + yy; if (ya > 128) ya = 128;
    yoff[yy] = (size_t)ya * 256;
  }
  for (int i = 0; i < 32; i++){
    int io = i * 32 + o;
    const float* pr = p1r + io * 16;
    const float* pim = p1i + io * 16;
    float hwr[4] = {0.f,0.f,0.f,0.f}, hwi[4] = {0.f,0.f,0.f,0.f};
#pragma unroll
    for (int k = 0; k < 16; k++){
      float a = -pr[k];
      float b = lamb - pim[k];
      float inv = 1.0f / fmaf(a, a, b * b);
      float px = a * inv, py = -b * inv;
      float4 r4 = R2r4[i*16 + k], i4 = R2i4[i*16 + k];
      hwr[0]=fmaf(px,r4.x,hwr[0]); hwr[0]=fmaf(-py,i4.x,hwr[0]);
      hwi[0]=fmaf(px,i4.x,hwi[0]); hwi[0]=fmaf( py,r4.x,hwi[0]);
      hwr[1]=fmaf(px,r4.y,hwr[1]); hwr[1]=fmaf(-py,i4.y,hwr[1]);
      hwi[1]=fmaf(px,i4.y,hwi[1]); hwi[1]=fmaf( py,r4.y,hwi[1]);
      hwr[2]=fmaf(px,r4.z,hwr[2]); hwr[2]=fmaf(-py,i4.z,hwr[2]);
      hwi[2]=fmaf(px,i4.z,hwi[2]); hwi[2]=fmaf( py,r4.z,hwi[2]);
      hwr[3]=fmaf(px,r4.w,hwr[3]); hwr[3]=fmaf(-py,i4.w,hwr[3]);
      hwi[3]=fmaf(px,i4.w,hwi[3]); hwi[3]=fmaf( py,r4.w,hwi[3]);
    }
    const c32* ab = alpha + (size_t)i * 129 * 256 + x;
#pragma unroll
    for (int b = 0; b < 8; b++){
      const c32* ap = ab + (size_t)b * 32 * 129 * 256;
#pragma unroll
      for (int yy = 0; yy < 4; yy++){
        c32 av = ap[yoff[yy]];
        acr[b][yy]=fmaf(av.x,hwr[yy],acr[b][yy]); acr[b][yy]=fmaf(-av.y,hwi[yy],acr[b][yy]);
        aci[b][yy]=fmaf(av.x,hwi[yy],aci[b][yy]); aci[b][yy]=fmaf( av.y,hwr[yy],aci[b][yy]);
      }
    }
  }
#pragma unroll
  for (int b = 0; b < 8; b++)
    for (int yy = 0; yy < yv; yy++)
      r1[(((size_t)(b*32 + o) * 129) + y0 + yy) * 256 + x] = make_float2(acr[b][yy], aci[b][yy]);
}

// ---------- r2[b,io,k,l]: phase1 VALU-clean (P2 transposed LDS rows, b128 broadcast), ----------
// ---------- phase2 all-thread x-split + shfl_xor reduce ----------
__global__ __launch_bounds__(256) void k_r2k(const c32* __restrict__ alpha,
                                             const float* __restrict__ p1r, const float* __restrict__ p1i,
                                             const c32* __restrict__ P2,
                                             const float* __restrict__ rr, const float* __restrict__ ri,
                                             c32* __restrict__ r2){
  __shared__ float Tr[NK2][257], Ti[NK2][257];
  __shared__ c32 P2s[NYF][10];     // [y][l], 9 + 1 pad -> 80B rows, 16B aligned
  int t = threadIdx.x;
  int bid = blockIdx.x;             // (b*CI+i)*CO + o
  int o = bid & 31; int bi = bid >> 5;
  int i = bi & 31;  int b = bi >> 5;
  int io = i * COut + o;
  for (int s = t; s < NK2 * NYF; s += 256){
    int y = s / 9, l = s - y * 9;
    P2s[y][l] = P2[(size_t)io * (NK2 * NYF) + l * NYF + y];
  }
  __syncthreads();
  { // phase 1: T[l][x=t] = sum_y alpha[bi,y,t] * P2s[y][l]
    float tr[9], ti[9];
#pragma unroll
    for (int l = 0; l < 9; l++){ tr[l] = 0.f; ti[l] = 0.f; }
    const c32* ap = alpha + (size_t)bi * NYF * 256 + t;
    c32 a_cur = ap[0];
    for (int y = 0; y < NYF; y++){
      c32 a = a_cur;
      if (y < NYF-1) a_cur = ap[(size_t)(y+1) * 256];
      const float4* prow = (const float4*)P2s[y];
      float4 q0 = prow[0], q1 = prow[1], q2 = prow[2], q3 = prow[3], q4 = prow[4];
      float pc[9], ps[9];
      pc[0]=q0.x; ps[0]=q0.y; pc[1]=q0.z; ps[1]=q0.w;
      pc[2]=q1.x; ps[2]=q1.y; pc[3]=q1.z; ps[3]=q1.w;
      pc[4]=q2.x; ps[4]=q2.y; pc[5]=q2.z; ps[5]=q2.w;
      pc[6]=q3.x; ps[6]=q3.y; pc[7]=q3.z; ps[7]=q3.w;
      pc[8]=q4.x; ps[8]=q4.y;
#pragma unroll
      for (int l = 0; l < 9; l++){
        tr[l] = fmaf(a.x, pc[l], tr[l]); tr[l] = fmaf(-a.y, ps[l], tr[l]);
        ti[l] = fmaf(a.x, ps[l], ti[l]); ti[l] = fmaf( a.y, pc[l], ti[l]);
      }
    }
#pragma unroll
    for (int l = 0; l < 9; l++){ Tr[l][t] = tr[l]; Ti[l][t] = ti[l]; }
  }
  __syncthreads();
  { // phase 2: r2[k,l] = -res[k,l] * sum_x P1[k,x]*T[l,x]
    int k = t >> 4, c = t & 15;
    float pa = -p1r[io*16 + k];
    float pb =  p1i[io*16 + k];
    float gr[9], gi[9];
#pragma unroll
    for (int l = 0; l < 9; l++){ gr[l] = 0.f; gi[l] = 0.f; }
#pragma unroll 4
    for (int jj = 0; jj < 16; jj++){
      int xx = c + 16*jj;
      float fx = (xx < 128) ? (float)xx : (float)(xx - 256);
      float bb = 6.2831853071795864f * fx - pb;
      float inv = 1.0f / fmaf(pa, pa, bb * bb);
      float px = pa * inv, py = -bb * inv;
#pragma unroll
      for (int l = 0; l < 9; l++){
        float trv = Tr[l][xx], tiv = Ti[l][xx];
        gr[l] = fmaf(px, trv, gr[l]); gr[l] = fmaf(-py, tiv, gr[l]);
        gi[l] = fmaf(px, tiv, gi[l]); gi[l] = fmaf( py, trv, gi[l]);
      }
    }
#pragma unroll
    for (int s = 1; s < 16; s <<= 1){
#pragma unroll
      for (int l = 0; l < 9; l++){
        gr[l] += __shfl_xor(gr[l], s, 64);
        gi[l] += __shfl_xor(gi[l], s, 64);
      }
    }
    if (c == 0){
#pragma unroll
      for (int l = 0; l < 9; l++){
        float resr = rr[(io*16 + k)*9 + l];
        float resi = ri[(io*16 + k)*9 + l];
        r2[((size_t)b * NIO + io) * NKL + k*9 + l] =
          make_float2(-(resr*gr[l] - resi*gi[l]), -(resr*gi[l] + resi*gr[l]));
      }
    }
  }
}

// ---------- x2 path: split-bf16 MFMA GEMM pipeline ----------
__global__ __launch_bounds__(256) void k_e2b(const float* __restrict__ p2r, const float* __restrict__ p2i,
                                             unsigned int* __restrict__ B){
  int o = blockIdx.x, w = threadIdx.x;
  float tt = (float)w * (1.0f / 256.0f);
  unsigned int* brow = B + ((size_t)o * 256 + w) * 576;   // 576 uints = 1152 halves
  for (int i = 0; i < 32; i++){
    int io = i * 32 + o;
#pragma unroll
    for (int l = 0; l < 9; l++){
      float pr = p2r[io*9 + l], pi = p2i[io*9 + l];
      float er = expf(pr * tt);
      float s, c; sincosf(pi * tt, &s, &c);
      float vr = er * c, vi = -er * s;
      unsigned short rh, rl, ih, il;
      split_bf(vr, rh, rl); split_bf(vi, ih, il);
      brow[i*9 + l]       = (unsigned int)rh | ((unsigned int)ih << 16);
      brow[288 + i*9 + l] = (unsigned int)rl | ((unsigned int)il << 16);
    }
  }
}

__global__ __launch_bounds__(256) void k_v(const c32* __restrict__ r2, const c32* __restrict__ E1,
                                           unsigned int* __restrict__ Ahi, unsigned int* __restrict__ Alo){
  int t = threadIdx.x;                 // z
  int j = blockIdx.x;                  // 256 = 8 xcd * 32
  int o = (j & 7) * 4 + ((j >> 3) & 3);
  int b = j >> 5;
  size_t rowoff = ((size_t)o * 2048 + b * 256 + t) * 288;
  unsigned int* AH = Ahi + rowoff;
  unsigned int* AL = Alo + rowoff;
  for (int i = 0; i < 32; i++){
    int io = i * 32 + o;
    const c32* e1p = E1 + (size_t)io * 16 * 256 + t;
    c32 e[16];
#pragma unroll
    for (int k = 0; k < 16; k++) e[k] = e1p[(size_t)k * 256];
    const c32* rp = r2 + ((size_t)b * NIO + io) * NKL;
#pragma unroll
    for (int l = 0; l < 9; l++){
      c32 acc = make_float2(0.0f, 0.0f);
#pragma unroll
      for (int k = 0; k < 16; k++) acc = cfma(rp[k*9 + l], e[k], acc);
      unsigned short rh, rl, ih, il;
      split_bf(acc.x, rh, rl); split_bf(acc.y, ih, il);
      AH[i*9 + l] = (unsigned int)rh | ((unsigned int)ih << 16);
      AL[i*9 + l] = (unsigned int)rl | ((unsigned int)il << 16);
    }
  }
}

// GEMM: per o: C[2048][256] += Re(A*B^T), split-bf16 3-product schedule, 54 K-chunks of 32.
#define ALO_H 37748736u
__global__ __launch_bounds__(256) void k_x2m(const unsigned short* __restrict__ A,
                                             const unsigned short* __restrict__ B,
                                             float* __restrict__ out){
  __shared__ __align__(16) unsigned short At[128*32];
  __shared__ __align__(16) unsigned short Bt[128*32];
  int t = threadIdx.x;
  int j = blockIdx.x;                   // 1024
  int orig = (j & 7) * 128 + (j >> 3);  // same-o blocks grouped per XCD
  int o  = orig >> 5;
  int mb = (orig >> 1) & 15;
  int nb = orig & 1;
  const unsigned short* Ab = A + ((size_t)o*2048 + mb*128 + (t>>2))*576 + (t&3)*8;
  const unsigned short* Bb = B + ((size_t)o*256  + nb*128 + (t>>2))*1152 + (t&3)*8;
  int ln = t & 63;
  int wm = t >> 7, wn = (t >> 6) & 1;
  int lrow = ln & 15, lk = (ln >> 4) * 8;
  f32x4 acc[4][4];
#pragma unroll
  for (int mi = 0; mi < 4; mi++)
#pragma unroll
    for (int ni = 0; ni < 4; ni++) acc[mi][ni] = (f32x4){0.f,0.f,0.f,0.f};

  for (int ks = 0; ks < 54; ks++){
    int kA = ks % 18;
    int kB = ks % 36;
    const unsigned short* Ap = Ab + (ks >= 36 ? (size_t)ALO_H : 0) + (size_t)kA*32;
    __syncthreads();
    GLOAD16(At + (size_t)t*8,        Ap);
    GLOAD16(At + 2048 + (size_t)t*8, Ap + (size_t)64*576);
    GLOAD16(Bt + (size_t)t*8,        Bb + (size_t)kB*32);
    GLOAD16(Bt + 2048 + (size_t)t*8, Bb + (size_t)kB*32 + (size_t)64*1152);
    __syncthreads();
    bf16x8 av[4], bv[4];
#pragma unroll
    for (int mi = 0; mi < 4; mi++)
      av[mi] = *(const bf16x8*)(At + (wm*64 + mi*16 + lrow)*32 + lk);
#pragma unroll
    for (int ni = 0; ni < 4; ni++)
      bv[ni] = *(const bf16x8*)(Bt + (wn*64 + ni*16 + lrow)*32 + lk);
#pragma unroll
    for (int mi = 0; mi < 4; mi++)
#pragma unroll
      for (int ni = 0; ni < 4; ni++)
        acc[mi][ni] = __builtin_amdgcn_mfma_f32_16x16x32_bf16(av[mi], bv[ni], acc[mi][ni], 0, 0, 0);
  }
  int nglob = nb*128 + wn*64 + (ln & 15);
#pragma unroll
  for (int mi = 0; mi < 4; mi++){
#pragma unroll
    for (int r = 0; r < 4; r++){
      int m = mb*128 + wm*64 + mi*16 + (ln >> 4)*4 + r;
      int b = m >> 8, z = m & 255;
      float* op = out + (((size_t)(b*32 + o) * 256 + z) * 256) + nglob;
#pragma unroll
      for (int ni = 0; ni < 4; ni++)
        op[ni*16] += acc[mi][ni][r];
    }
  }
}

extern "C" void kernel_launch(void* const* d_in, const int* in_sizes, int n_in,
                              void* d_out, int out_size, void* d_ws, size_t ws_size,
                              hipStream_t stream){
  const float* x    = (const float*)d_in[0];
  const float* rr   = (const float*)d_in[1];
  const float* ri   = (const float*)d_in[2];
  const float* p1r  = (const float*)d_in[3];
  const float* p1i  = (const float*)d_in[4];
  const float* p2r  = (const float*)d_in[5];
  const float* p2i  = (const float*)d_in[6];
  const float* bias = (const float*)d_in[7];
  float* out = (float*)d_out;

  // ws layout kept byte-identical (holes where P1/R2b used to live)
  char* ws = (char*)d_ws;
  size_t off = 0;
  c32* alpha = (c32*)(ws + off); off += (size_t)NB * CIn * NYF * NN1 * sizeof(c32);   // 67.6 MB
  c32* r1b   = (c32*)(ws + off); off += (size_t)NB * COut * NYF * NN1 * sizeof(c32);  // 67.6 MB
  off += (size_t)NIO * NK1 * NN1 * sizeof(c32);                                       // (hole)
  c32* P2b   = (c32*)(ws + off); off += (size_t)NIO * NK2 * NYF * sizeof(c32);        //  9.5 MB
  off += (size_t)NIO * NK1 * NYF * sizeof(c32);                                       // (hole)
  c32* E1b   = (c32*)(ws + off); off += (size_t)NIO * NK1 * NN1 * sizeof(c32);        // 33.6 MB
  c32* r2b   = (c32*)(ws + off); off += (size_t)NB * NIO * NKL * sizeof(c32);         //  9.4 MB
  float2* tw = (float2*)(ws + off); off += 256 * sizeof(float2);
  unsigned short* Abf  = (unsigned short*)(ws + 0);
  unsigned short* E2bf = (unsigned short*)(ws + 150994944);

  k_tw<<<1, 256, 0, stream>>>(tw);
  k_p2<<<(NIO * NK2 * NYF + 255) / 256, 256, 0, stream>>>(p2r, p2i, P2b);
  k_e1<<<NIO * NK1, 256, 0, stream>>>(p1r, p1i, E1b);

  k_fwd_y<<<NB * CIn * 8, 256, 0, stream>>>(x, tw, alpha);
  k_fft_x<0><<<NB * CIn * NYF / 16, 256, 0, stream>>>(tw, alpha);

  k_r1<<<1056, 256, 0, stream>>>(alpha, rr, ri, p1r, p1i, P2b, r1b);
  k_r2k<<<NB * CIn * COut, 256, 0, stream>>>(alpha, p1r, p1i, P2b, rr, ri, r2b);

  k_fft_x<1><<<NB * COut * NYF / 16, 256, 0, stream>>>(tw, r1b);
  k_inv_y<<<NB * COut * 8, 256, 0, stream>>>(r1b, bias, tw, out);

  k_e2b<<<32, 256, 0, stream>>>(p2r, p2i, (unsigned int*)E2bf);
  k_v<<<256, 256, 0, stream>>>(r2b, E1b, (unsigned int*)Abf, (unsigned int*)(Abf + ALO_H));
  k_x2m<<<1024, 256, 0, stream>>>(Abf, E2bf, out);
}

// Round 8
// 1174.235 us; speedup vs baseline: 1.6759x; 1.1910x over previous
//
#include <hip/hip_runtime.h>
#include <math.h>

#define NB 8
#define CIn 32
#define COut 32
#define NIO 1024      // CIn*CO
#define NN1 256
#define NN2 256
#define NYF 129       // NN2/2+1
#define NK1 16
#define NK2 9
#define NKL 144       // NK1*NK2

typedef float2 c32;
typedef __attribute__((ext_vector_type(8))) __bf16 bf16x8;
typedef __attribute__((ext_vector_type(4))) float f32x4;

__device__ __forceinline__ c32 cadd(c32 a, c32 b){ return make_float2(a.x+b.x, a.y+b.y); }
__device__ __forceinline__ c32 csub(c32 a, c32 b){ return make_float2(a.x-b.x, a.y-b.y); }
__device__ __forceinline__ c32 cmul(c32 a, c32 b){ return make_float2(a.x*b.x - a.y*b.y, a.x*b.y + a.y*b.x); }
__device__ __forceinline__ c32 cfma(c32 a, c32 b, c32 acc){
  acc.x = fmaf(a.x, b.x, acc.x); acc.x = fmaf(-a.y, b.y, acc.x);
  acc.y = fmaf(a.x, b.y, acc.y); acc.y = fmaf(a.y, b.x, acc.y);
  return acc;
}
__device__ __forceinline__ unsigned short f2bf(float f){
  unsigned int u = __float_as_uint(f);
  u += 0x7FFF + ((u >> 16) & 1);
  return (unsigned short)(u >> 16);
}
__device__ __forceinline__ float bf2f(unsigned short h){
  unsigned int u = ((unsigned int)h) << 16;
  return __uint_as_float(u);
}
__device__ __forceinline__ void split_bf(float f, unsigned short& hi, unsigned short& lo){
  hi = f2bf(f);
  lo = f2bf(f - bf2f(hi));
}

#define GLOAD16(lptr, gptr) \
  __builtin_amdgcn_global_load_lds((const __attribute__((address_space(1))) unsigned int*)(gptr), \
                                   (__attribute__((address_space(3))) unsigned int*)(lptr), 16, 0, 0)

// ---------------- FFT-256 via four-step radix-16 ----------------
template<int INV> __device__ __forceinline__ c32 rot90(c32 a){
  return INV ? make_float2(-a.y, a.x) : make_float2(a.y, -a.x);
}
template<int INV> __device__ __forceinline__ void dft4(c32& a0, c32& a1, c32& a2, c32& a3){
  c32 t0 = cadd(a0,a2), t1 = csub(a0,a2);
  c32 t2 = cadd(a1,a3), t3 = rot90<INV>(csub(a1,a3));
  a0 = cadd(t0,t2); a1 = cadd(t1,t3); a2 = csub(t0,t2); a3 = csub(t1,t3);
}
__device__ __forceinline__ int SLOT16(int k){ return 4*(k&3) + (k>>2); }
template<int INV> __device__ __forceinline__ c32 twg(const float2* ltw, int idx){
  float2 w = ltw[idx & 255];
  return INV ? make_float2(w.x, w.y) : make_float2(w.x, -w.y);
}
template<int INV> __device__ __forceinline__ void fft16r(c32 v[16], const float2* ltw){
#pragma unroll
  for (int bp = 0; bp < 4; bp++) dft4<INV>(v[bp], v[4+bp], v[8+bp], v[12+bp]);
#pragma unroll
  for (int c = 1; c < 4; c++)
#pragma unroll
    for (int bp = 1; bp < 4; bp++)
      v[4*c+bp] = cmul(v[4*c+bp], twg<INV>(ltw, 16*bp*c));
#pragma unroll
  for (int c = 0; c < 4; c++) dft4<INV>(v[4*c], v[4*c+1], v[4*c+2], v[4*c+3]);
}
template<int INV>
__device__ __forceinline__ void fft256_core(c32 v[16], int b, c32* tile, const float2* ltw){
  fft16r<INV>(v, ltw);
#pragma unroll
  for (int c = 0; c < 16; c++){
    c32 g = (c && b) ? cmul(v[SLOT16(c)], twg<INV>(ltw, b*c)) : v[SLOT16(c)];
    tile[c*17 + b] = g;
  }
  __syncthreads();
#pragma unroll
  for (int j = 0; j < 16; j++) v[j] = tile[b*17 + j];
  fft16r<INV>(v, ltw);
}

// ---------- precompute tables ----------
__global__ void k_tw(float2* __restrict__ tw){
  int m = threadIdx.x;
  double ang = 6.283185307179586 * (double)m / 256.0;
  tw[m] = make_float2((float)cos(ang), (float)sin(ang));
}

__global__ void k_p2(const float* __restrict__ p2r, const float* __restrict__ p2i, c32* __restrict__ P2){
  int idx = blockIdx.x * 256 + threadIdx.x;
  if (idx >= NIO * NK2 * NYF) return;
  int y = idx % NYF; int iol = idx / NYF;
  float a = -p2r[iol];
  float b = 6.2831853071795864f * (float)y - p2i[iol];
  float inv = 1.0f / fmaf(a, a, b * b);
  P2[idx] = make_float2(a * inv, -b * inv);
}

__global__ void k_e1(const float* __restrict__ p1r, const float* __restrict__ p1i, c32* __restrict__ E1){
  int idx = blockIdx.x * 256 + threadIdx.x;
  int z = idx & 255; int iok = idx >> 8;
  float t = (float)z * (1.0f / 256.0f);
  float er = expf(p1r[iok] * t);
  float s, c; sincosf(p1i[iok] * t, &s, &c);
  E1[idx] = make_float2(er * c, er * s);
}

// ---------- forward: rfft along n2 (paired rows), write alpha[(bi*129+y)*256+n1], scaled 1/65536 ----------
__global__ __launch_bounds__(256) void k_fwd_y(const float* __restrict__ x, const float2* __restrict__ tw,
                                               c32* __restrict__ alpha){
  __shared__ c32 tile[16*272];
  __shared__ float2 ltw[256];
  int t = threadIdx.x;
  ltw[t] = tw[t];
  int bi = blockIdx.x >> 3;
  int n1c = (blockIdx.x & 7) << 5;
  int row = t >> 4, b = t & 15;
  const float* xe = x + ((size_t)bi * 256 + n1c + 2 * row) * 256;
  c32 v[16];
#pragma unroll
  for (int a = 0; a < 16; a++)
    v[a] = make_float2(xe[16*a + b], xe[256 + 16*a + b]);
  __syncthreads();
  fft256_core<0>(v, b, tile + row*272, ltw);
  __syncthreads();
#pragma unroll
  for (int d = 0; d < 16; d++)
    tile[row*272 + b + 16*d] = v[SLOT16(d)];
  __syncthreads();
  const float sc = 0.5f / 65536.0f;
#pragma unroll
  for (int j = 0; j < 8; j++){
    int item = t + 256*j;
    int h = item & 127, r2 = item >> 7;
    c32* Zb = tile + r2*272;
    if (h == 0){
      c32 z0 = Zb[0], z1 = Zb[128];
      Zb[0]   = make_float2(z0.x * (2.0f*sc), z0.y * (2.0f*sc));
      Zb[128] = make_float2(z1.x * (2.0f*sc), z1.y * (2.0f*sc));
    } else {
      c32 zk = Zb[h], zm = Zb[256 - h];
      c32 A = make_float2(sc*(zk.x + zm.x), sc*(zk.y - zm.y));
      c32 B = make_float2(sc*(zk.y + zm.y), sc*(zm.x - zk.x));
      Zb[h] = A; Zb[256 - h] = B;
    }
  }
  __syncthreads();
  for (int j = 0; j < 17; j++){
    int idx = t + 256*j;
    if (idx >= 129*32) break;
    int y = idx >> 5, n1i = idx & 31;
    c32* Zb = tile + (n1i >> 1)*272;
    c32 val;
    if ((n1i & 1) == 0)
      val = (y == 0) ? make_float2(Zb[0].x, 0.0f)
          : (y == 128) ? make_float2(Zb[128].x, 0.0f) : Zb[y];
    else
      val = (y == 0) ? make_float2(Zb[0].y, 0.0f)
          : (y == 128) ? make_float2(Zb[128].y, 0.0f) : Zb[256 - y];
    alpha[((size_t)bi * 129 + y) * 256 + n1c + n1i] = val;
  }
}

// ---------- complex FFT-256 on contiguous rows, in place ----------
template<int INV>
__global__ __launch_bounds__(256) void k_fft_x(const float2* __restrict__ tw, c32* __restrict__ buf){
  __shared__ c32 tile[16*272];
  __shared__ float2 ltw[256];
  int t = threadIdx.x;
  ltw[t] = tw[t];
  int row = t >> 4, b = t & 15;
  c32* p = buf + ((size_t)blockIdx.x * 16 + row) * 256;
  c32 v[16];
#pragma unroll
  for (int a = 0; a < 16; a++) v[a] = p[16*a + b];
  __syncthreads();
  fft256_core<INV>(v, b, tile + row*272, ltw);
#pragma unroll
  for (int d = 0; d < 16; d++) p[b + 16*d] = v[SLOT16(d)];
}

// ---------- inverse rfft along y (paired z-columns) + bias, writes out ----------
__global__ __launch_bounds__(256) void k_inv_y(const c32* __restrict__ r1, const float* __restrict__ bias,
                                               const float2* __restrict__ tw, float* __restrict__ out){
  __shared__ c32 tile[16*272];
  __shared__ float2 ltw[256];
  c32* SA = tile;
  int t = threadIdx.x;
  ltw[t] = tw[t];
  int bo = blockIdx.x >> 3;
  int z0 = (blockIdx.x & 7) << 5;
  for (int j = 0; j < 17; j++){
    int idx = t + 256*j;
    if (idx >= 129*32) break;
    int y = idx >> 5, zi = idx & 31;
    SA[y*33 + zi] = r1[((size_t)bo * 129 + y) * 256 + z0 + zi];
  }
  __syncthreads();
  int p = t >> 4, b = t & 15;
  c32 v[16];
#pragma unroll
  for (int a = 0; a < 16; a++){
    int k = 16*a + b;
    int m = (k <= 128) ? k : 256 - k;
    c32 A = SA[m*33 + 2*p], B = SA[m*33 + 2*p + 1];
    if (k == 0 || k == 128)  v[a] = make_float2(A.x, B.x);
    else if (k < 128)        v[a] = make_float2(A.x - B.y, A.y + B.x);
    else                     v[a] = make_float2(A.x + B.y, B.x - A.y);
  }
  __syncthreads();
  fft256_core<1>(v, b, tile + p*272, ltw);
  float bv = bias[bo & 31];
  float* o0 = out + ((size_t)bo * 256 + z0 + 2*p) * 256;
#pragma unroll
  for (int d = 0; d < 16; d++){
    c32 zz = v[SLOT16(d)];
    o0[b + 16*d]       = zz.x + bv;
    o0[256 + b + 16*d] = zz.y + bv;
  }
}

// ---------- mode mixing r1: poles on-the-fly, R2 staged in LDS, 4-y tile ----------
__global__ __launch_bounds__(256, 4) void k_r1(const c32* __restrict__ alpha,
                                               const float* __restrict__ rr, const float* __restrict__ ri,
                                               const float* __restrict__ p1r, const float* __restrict__ p1i,
                                               const c32* __restrict__ P2,
                                               c32* __restrict__ r1){
  __shared__ float4 R2r4[512], R2i4[512];    // [i*16+k] -> 4 y's
  int t = threadIdx.x;
  int j = blockIdx.x;
  int g = (j & 7) * 132 + (j >> 3);          // XCD-chunked
  int y4 = g >> 5, o = g & 31;               // y4: 0..32
  int y0 = y4 * 4;
  int yv = (y0 + 4 <= 129) ? 4 : (129 - y0);
  float* R2r = (float*)R2r4; float* R2i = (float*)R2i4;
#pragma unroll
  for (int e = 0; e < 8; e++){
    int flat = t + e * 256;                  // i*64 + k*4 + yy
    int i = flat >> 6, k = (flat >> 2) & 15, yy = flat & 3;
    int io = i * 32 + o;
    int iok = io * 16 + k;
    int ya = y0 + yy; if (ya > 128) ya = 128;
    float ar = 0.f, ai = 0.f;
#pragma unroll
    for (int l = 0; l < 9; l++){
      float rsr = rr[iok*9 + l], rsi = ri[iok*9 + l];
      c32 p2 = P2[((size_t)io*9 + l)*129 + ya];
      ar = fmaf(rsr, p2.x, ar); ar = fmaf(-rsi, p2.y, ar);
      ai = fmaf(rsr, p2.y, ai); ai = fmaf(rsi, p2.x, ai);
    }
    R2r[flat] = ar; R2i[flat] = ai;
  }
  __syncthreads();
  int x = t;
  float fx = (x < 128) ? (float)x : (float)(x - 256);
  float lamb = 6.2831853071795864f * fx;
  float acr[8][4], aci[8][4];
#pragma unroll
  for (int b = 0; b < 8; b++)
#pragma unroll
    for (int yy = 0; yy < 4; yy++){ acr[b][yy] = 0.f; aci[b][yy] = 0.f; }
  size_t yoff[4];
#pragma unroll
  for (int yy = 0; yy < 4; yy++){
    int ya = y0 + yy; if (ya > 128) ya = 128;
    yoff[yy] = (size_t)ya * 256;
  }
  for (int i = 0; i < 32; i++){
    int io = i * 32 + o;
    const float* pr = p1r + io * 16;
    const float* pim = p1i + io * 16;
    float hwr[4] = {0.f,0.f,0.f,0.f}, hwi[4] = {0.f,0.f,0.f,0.f};
#pragma unroll
    for (int k = 0; k < 16; k++){
      float a = -pr[k];
      float b = lamb - pim[k];
      float inv = 1.0f / fmaf(a, a, b * b);
      float px = a * inv, py = -b * inv;
      float4 r4 = R2r4[i*16 + k], i4 = R2i4[i*16 + k];
      hwr[0]=fmaf(px,r4.x,hwr[0]); hwr[0]=fmaf(-py,i4.x,hwr[0]);
      hwi[0]=fmaf(px,i4.x,hwi[0]); hwi[0]=fmaf( py,r4.x,hwi[0]);
      hwr[1]=fmaf(px,r4.y,hwr[1]); hwr[1]=fmaf(-py,i4.y,hwr[1]);
      hwi[1]=fmaf(px,i4.y,hwi[1]); hwi[1]=fmaf( py,r4.y,hwi[1]);
      hwr[2]=fmaf(px,r4.z,hwr[2]); hwr[2]=fmaf(-py,i4.z,hwr[2]);
      hwi[2]=fmaf(px,i4.z,hwi[2]); hwi[2]=fmaf( py,r4.z,hwi[2]);
      hwr[3]=fmaf(px,r4.w,hwr[3]); hwr[3]=fmaf(-py,i4.w,hwr[3]);
      hwi[3]=fmaf(px,i4.w,hwi[3]); hwi[3]=fmaf( py,r4.w,hwi[3]);
    }
    const c32* ab = alpha + (size_t)i * 129 * 256 + x;
#pragma unroll
    for (int b = 0; b < 8; b++){
      const c32* ap = ab + (size_t)b * 32 * 129 * 256;
#pragma unroll
      for (int yy = 0; yy < 4; yy++){
        c32 av = ap[yoff[yy]];
        acr[b][yy]=fmaf(av.x,hwr[yy],acr[b][yy]); acr[b][yy]=fmaf(-av.y,hwi[yy],acr[b][yy]);
        aci[b][yy]=fmaf(av.x,hwi[yy],aci[b][yy]); aci[b][yy]=fmaf( av.y,hwr[yy],aci[b][yy]);
      }
    }
  }
#pragma unroll
  for (int b = 0; b < 8; b++)
    for (int yy = 0; yy < yv; yy++)
      r1[(((size_t)(b*32 + o) * 129) + y0 + yy) * 256 + x] = make_float2(acr[b][yy], aci[b][yy]);
}

// ---------- r2[b,io,k,l]: XCD-grouped grid + 4-deep alpha prefetch ----------
__global__ __launch_bounds__(256) void k_r2k(const c32* __restrict__ alpha,
                                             const float* __restrict__ p1r, const float* __restrict__ p1i,
                                             const c32* __restrict__ P2,
                                             const float* __restrict__ rr, const float* __restrict__ ri,
                                             c32* __restrict__ r2){
  __shared__ float Tr[NK2][257], Ti[NK2][257];
  __shared__ c32 P2s[NYF][10];     // [y][l], 9 + 1 pad -> 80B rows, 16B aligned
  int t = threadIdx.x;
  int j = blockIdx.x;               // 8192 = 8 XCD * 1024
  int bid = (j & 7) * 1024 + (j >> 3);  // same-bi (32 o's) consecutive per XCD
  int o = bid & 31; int bi = bid >> 5;
  int i = bi & 31;  int b = bi >> 5;
  int io = i * COut + o;
  for (int s = t; s < NK2 * NYF; s += 256){
    int y = s / 9, l = s - y * 9;
    P2s[y][l] = P2[(size_t)io * (NK2 * NYF) + l * NYF + y];
  }
  __syncthreads();
  { // phase 1: T[l][x=t] = sum_y alpha[bi,y,t] * P2s[y][l]
    float tr[9], ti[9];
#pragma unroll
    for (int l = 0; l < 9; l++){ tr[l] = 0.f; ti[l] = 0.f; }
    const c32* ap = alpha + (size_t)bi * NYF * 256 + t;
    c32 a_pre[4];
#pragma unroll
    for (int q = 0; q < 4; q++) a_pre[q] = ap[(size_t)q * 256];
    for (int yb = 0; yb < NYF; yb += 4){
#pragma unroll
      for (int q = 0; q < 4; q++){
        int y = yb + q;
        if (y >= NYF) break;
        c32 a = a_pre[q];
        int yn = y + 4;
        if (yn < NYF) a_pre[q] = ap[(size_t)yn * 256];
        const float4* prow = (const float4*)P2s[y];
        float4 q0 = prow[0], q1 = prow[1], q2 = prow[2], q3 = prow[3], q4 = prow[4];
        float pc[9], ps[9];
        pc[0]=q0.x; ps[0]=q0.y; pc[1]=q0.z; ps[1]=q0.w;
        pc[2]=q1.x; ps[2]=q1.y; pc[3]=q1.z; ps[3]=q1.w;
        pc[4]=q2.x; ps[4]=q2.y; pc[5]=q2.z; ps[5]=q2.w;
        pc[6]=q3.x; ps[6]=q3.y; pc[7]=q3.z; ps[7]=q3.w;
        pc[8]=q4.x; ps[8]=q4.y;
#pragma unroll
        for (int l = 0; l < 9; l++){
          tr[l] = fmaf(a.x, pc[l], tr[l]); tr[l] = fmaf(-a.y, ps[l], tr[l]);
          ti[l] = fmaf(a.x, ps[l], ti[l]); ti[l] = fmaf( a.y, pc[l], ti[l]);
        }
      }
    }
#pragma unroll
    for (int l = 0; l < 9; l++){ Tr[l][t] = tr[l]; Ti[l][t] = ti[l]; }
  }
  __syncthreads();
  { // phase 2: r2[k,l] = -res[k,l] * sum_x P1[k,x]*T[l,x]
    int k = t >> 4, c = t & 15;
    float pa = -p1r[io*16 + k];
    float pb =  p1i[io*16 + k];
    float gr[9], gi[9];
#pragma unroll
    for (int l = 0; l < 9; l++){ gr[l] = 0.f; gi[l] = 0.f; }
#pragma unroll 4
    for (int jj = 0; jj < 16; jj++){
      int xx = c + 16*jj;
      float fx = (xx < 128) ? (float)xx : (float)(xx - 256);
      float bb = 6.2831853071795864f * fx - pb;
      float inv = 1.0f / fmaf(pa, pa, bb * bb);
      float px = pa * inv, py = -bb * inv;
#pragma unroll
      for (int l = 0; l < 9; l++){
        float trv = Tr[l][xx], tiv = Ti[l][xx];
        gr[l] = fmaf(px, trv, gr[l]); gr[l] = fmaf(-py, tiv, gr[l]);
        gi[l] = fmaf(px, tiv, gi[l]); gi[l] = fmaf( py, trv, gi[l]);
      }
    }
#pragma unroll
    for (int s = 1; s < 16; s <<= 1){
#pragma unroll
      for (int l = 0; l < 9; l++){
        gr[l] += __shfl_xor(gr[l], s, 64);
        gi[l] += __shfl_xor(gi[l], s, 64);
      }
    }
    if (c == 0){
#pragma unroll
      for (int l = 0; l < 9; l++){
        float resr = rr[(io*16 + k)*9 + l];
        float resi = ri[(io*16 + k)*9 + l];
        r2[((size_t)b * NIO + io) * NKL + k*9 + l] =
          make_float2(-(resr*gr[l] - resi*gi[l]), -(resr*gi[l] + resi*gr[l]));
      }
    }
  }
}

// ---------- x2 path: split-bf16 MFMA GEMM pipeline ----------
// k_e2b: 256 blocks = (ic 0..7) x (o 0..31); each handles 4 i values
__global__ __launch_bounds__(256) void k_e2b(const float* __restrict__ p2r, const float* __restrict__ p2i,
                                             unsigned int* __restrict__ B){
  int j = blockIdx.x;
  int o = j & 31, ic = j >> 5;
  int w = threadIdx.x;
  float tt = (float)w * (1.0f / 256.0f);
  unsigned int* brow = B + ((size_t)o * 256 + w) * 576;   // 576 uints = 1152 halves
#pragma unroll
  for (int ii = 0; ii < 4; ii++){
    int i = ic * 4 + ii;
    int io = i * 32 + o;
#pragma unroll
    for (int l = 0; l < 9; l++){
      float pr = p2r[io*9 + l], pi = p2i[io*9 + l];
      float er = expf(pr * tt);
      float s, c; sincosf(pi * tt, &s, &c);
      float vr = er * c, vi = -er * s;
      unsigned short rh, rl, ih, il;
      split_bf(vr, rh, rl); split_bf(vi, ih, il);
      brow[i*9 + l]       = (unsigned int)rh | ((unsigned int)ih << 16);
      brow[288 + i*9 + l] = (unsigned int)rl | ((unsigned int)il << 16);
    }
  }
}

// k_v: 1024 blocks = (ic 0..3) x (b 0..7) x (o 0..31); each handles 8 i values
__global__ __launch_bounds__(256) void k_v(const c32* __restrict__ r2, const c32* __restrict__ E1,
                                           unsigned int* __restrict__ Ahi, unsigned int* __restrict__ Alo){
  int t = threadIdx.x;                 // z
  int j = blockIdx.x;                  // 1024
  int o = j & 31;
  int rest = j >> 5;                   // 0..31
  int b = rest & 7, ic = rest >> 3;    // ic 0..3
  size_t rowoff = ((size_t)o * 2048 + b * 256 + t) * 288;
  unsigned int* AH = Ahi + rowoff;
  unsigned int* AL = Alo + rowoff;
#pragma unroll 1
  for (int ii = 0; ii < 8; ii++){
    int i = ic * 8 + ii;
    int io = i * 32 + o;
    const c32* e1p = E1 + (size_t)io * 16 * 256 + t;
    c32 e[16];
#pragma unroll
    for (int k = 0; k < 16; k++) e[k] = e1p[(size_t)k * 256];
    const c32* rp = r2 + ((size_t)b * NIO + io) * NKL;
#pragma unroll
    for (int l = 0; l < 9; l++){
      c32 acc = make_float2(0.0f, 0.0f);
#pragma unroll
      for (int k = 0; k < 16; k++) acc = cfma(rp[k*9 + l], e[k], acc);
      unsigned short rh, rl, ih, il;
      split_bf(acc.x, rh, rl); split_bf(acc.y, ih, il);
      AH[i*9 + l] = (unsigned int)rh | ((unsigned int)ih << 16);
      AL[i*9 + l] = (unsigned int)rl | ((unsigned int)il << 16);
    }
  }
}

// GEMM: per o: C[2048][256] += Re(A*B^T), split-bf16 3-product schedule, 54 K-chunks of 32.
#define ALO_H 37748736u
__global__ __launch_bounds__(256) void k_x2m(const unsigned short* __restrict__ A,
                                             const unsigned short* __restrict__ B,
                                             float* __restrict__ out){
  __shared__ __align__(16) unsigned short At[128*32];
  __shared__ __align__(16) unsigned short Bt[128*32];
  int t = threadIdx.x;
  int j = blockIdx.x;                   // 1024
  int orig = (j & 7) * 128 + (j >> 3);  // same-o blocks grouped per XCD
  int o  = orig >> 5;
  int mb = (orig >> 1) & 15;
  int nb = orig & 1;
  const unsigned short* Ab = A + ((size_t)o*2048 + mb*128 + (t>>2))*576 + (t&3)*8;
  const unsigned short* Bb = B + ((size_t)o*256  + nb*128 + (t>>2))*1152 + (t&3)*8;
  int ln = t & 63;
  int wm = t >> 7, wn = (t >> 6) & 1;
  int lrow = ln & 15, lk = (ln >> 4) * 8;
  f32x4 acc[4][4];
#pragma unroll
  for (int mi = 0; mi < 4; mi++)
#pragma unroll
    for (int ni = 0; ni < 4; ni++) acc[mi][ni] = (f32x4){0.f,0.f,0.f,0.f};

  for (int ks = 0; ks < 54; ks++){
    int kA = ks % 18;
    int kB = ks % 36;
    const unsigned short* Ap = Ab + (ks >= 36 ? (size_t)ALO_H : 0) + (size_t)kA*32;
    __syncthreads();
    GLOAD16(At + (size_t)t*8,        Ap);
    GLOAD16(At + 2048 + (size_t)t*8, Ap + (size_t)64*576);
    GLOAD16(Bt + (size_t)t*8,        Bb + (size_t)kB*32);
    GLOAD16(Bt + 2048 + (size_t)t*8, Bb + (size_t)kB*32 + (size_t)64*1152);
    __syncthreads();
    bf16x8 av[4], bv[4];
#pragma unroll
    for (int mi = 0; mi < 4; mi++)
      av[mi] = *(const bf16x8*)(At + (wm*64 + mi*16 + lrow)*32 + lk);
#pragma unroll
    for (int ni = 0; ni < 4; ni++)
      bv[ni] = *(const bf16x8*)(Bt + (wn*64 + ni*16 + lrow)*32 + lk);
#pragma unroll
    for (int mi = 0; mi < 4; mi++)
#pragma unroll
      for (int ni = 0; ni < 4; ni++)
        acc[mi][ni] = __builtin_amdgcn_mfma_f32_16x16x32_bf16(av[mi], bv[ni], acc[mi][ni], 0, 0, 0);
  }
  int nglob = nb*128 + wn*64 + (ln & 15);
#pragma unroll
  for (int mi = 0; mi < 4; mi++){
#pragma unroll
    for (int r = 0; r < 4; r++){
      int m = mb*128 + wm*64 + mi*16 + (ln >> 4)*4 + r;
      int b = m >> 8, z = m & 255;
      float* op = out + (((size_t)(b*32 + o) * 256 + z) * 256) + nglob;
#pragma unroll
      for (int ni = 0; ni < 4; ni++)
        op[ni*16] += acc[mi][ni][r];
    }
  }
}

extern "C" void kernel_launch(void* const* d_in, const int* in_sizes, int n_in,
                              void* d_out, int out_size, void* d_ws, size_t ws_size,
                              hipStream_t stream){
  const float* x    = (const float*)d_in[0];
  const float* rr   = (const float*)d_in[1];
  const float* ri   = (const float*)d_in[2];
  const float* p1r  = (const float*)d_in[3];
  const float* p1i  = (const float*)d_in[4];
  const float* p2r  = (const float*)d_in[5];
  const float* p2i  = (const float*)d_in[6];
  const float* bias = (const float*)d_in[7];
  float* out = (float*)d_out;

  // ws layout kept byte-identical (holes where P1/R2b used to live)
  char* ws = (char*)d_ws;
  size_t off = 0;
  c32* alpha = (c32*)(ws + off); off += (size_t)NB * CIn * NYF * NN1 * sizeof(c32);   // 67.6 MB
  c32* r1b   = (c32*)(ws + off); off += (size_t)NB * COut * NYF * NN1 * sizeof(c32);  // 67.6 MB
  off += (size_t)NIO * NK1 * NN1 * sizeof(c32);                                       // (hole)
  c32* P2b   = (c32*)(ws + off); off += (size_t)NIO * NK2 * NYF * sizeof(c32);        //  9.5 MB
  off += (size_t)NIO * NK1 * NYF * sizeof(c32);                                       // (hole)
  c32* E1b   = (c32*)(ws + off); off += (size_t)NIO * NK1 * NN1 * sizeof(c32);        // 33.6 MB
  c32* r2b   = (c32*)(ws + off); off += (size_t)NB * NIO * NKL * sizeof(c32);         //  9.4 MB
  float2* tw = (float2*)(ws + off); off += 256 * sizeof(float2);
  unsigned short* Abf  = (unsigned short*)(ws + 0);
  unsigned short* E2bf = (unsigned short*)(ws + 150994944);

  k_tw<<<1, 256, 0, stream>>>(tw);
  k_p2<<<(NIO * NK2 * NYF + 255) / 256, 256, 0, stream>>>(p2r, p2i, P2b);
  k_e1<<<NIO * NK1, 256, 0, stream>>>(p1r, p1i, E1b);

  k_fwd_y<<<NB * CIn * 8, 256, 0, stream>>>(x, tw, alpha);
  k_fft_x<0><<<NB * CIn * NYF / 16, 256, 0, stream>>>(tw, alpha);

  k_r1<<<1056, 256, 0, stream>>>(alpha, rr, ri, p1r, p1i, P2b, r1b);
  k_r2k<<<NB * CIn * COut, 256, 0, stream>>>(alpha, p1r, p1i, P2b, rr, ri, r2b);

  k_fft_x<1><<<NB * COut * NYF / 16, 256, 0, stream>>>(tw, r1b);
  k_inv_y<<<NB * COut * 8, 256, 0, stream>>>(r1b, bias, tw, out);

  k_e2b<<<256, 256, 0, stream>>>(p2r, p2i, (unsigned int*)E2bf);
  k_v<<<1024, 256, 0, stream>>>(r2b, E1b, (unsigned int*)Abf, (unsigned int*)(Abf + ALO_H));
  k_x2m<<<1024, 256, 0, stream>>>(Abf, E2bf, out);
}

// Round 9
// 1039.828 us; speedup vs baseline: 1.8925x; 1.1293x over previous
//
#include <hip/hip_runtime.h>
#include <math.h>

#define NB 8
#define CIn 32
#define COut 32
#define NIO 1024      // CIn*CO
#define NN1 256
#define NN2 256
#define NYF 129       // NN2/2+1
#define NK1 16
#define NK2 9
#define NKL 144       // NK1*NK2

typedef float2 c32;
typedef __attribute__((ext_vector_type(8))) __bf16 bf16x8;
typedef __attribute__((ext_vector_type(4))) float f32x4;

__device__ __forceinline__ c32 cadd(c32 a, c32 b){ return make_float2(a.x+b.x, a.y+b.y); }
__device__ __forceinline__ c32 csub(c32 a, c32 b){ return make_float2(a.x-b.x, a.y-b.y); }
__device__ __forceinline__ c32 cmul(c32 a, c32 b){ return make_float2(a.x*b.x - a.y*b.y, a.x*b.y + a.y*b.x); }
__device__ __forceinline__ c32 cfma(c32 a, c32 b, c32 acc){
  acc.x = fmaf(a.x, b.x, acc.x); acc.x = fmaf(-a.y, b.y, acc.x);
  acc.y = fmaf(a.x, b.y, acc.y); acc.y = fmaf(a.y, b.x, acc.y);
  return acc;
}
__device__ __forceinline__ unsigned short f2bf(float f){
  unsigned int u = __float_as_uint(f);
  u += 0x7FFF + ((u >> 16) & 1);
  return (unsigned short)(u >> 16);
}
__device__ __forceinline__ float bf2f(unsigned short h){
  unsigned int u = ((unsigned int)h) << 16;
  return __uint_as_float(u);
}
__device__ __forceinline__ void split_bf(float f, unsigned short& hi, unsigned short& lo){
  hi = f2bf(f);
  lo = f2bf(f - bf2f(hi));
}

#define GLOAD16(lptr, gptr) \
  __builtin_amdgcn_global_load_lds((const __attribute__((address_space(1))) unsigned int*)(gptr), \
                                   (__attribute__((address_space(3))) unsigned int*)(lptr), 16, 0, 0)

// ---------------- FFT-256 via four-step radix-16 ----------------
template<int INV> __device__ __forceinline__ c32 rot90(c32 a){
  return INV ? make_float2(-a.y, a.x) : make_float2(a.y, -a.x);
}
template<int INV> __device__ __forceinline__ void dft4(c32& a0, c32& a1, c32& a2, c32& a3){
  c32 t0 = cadd(a0,a2), t1 = csub(a0,a2);
  c32 t2 = cadd(a1,a3), t3 = rot90<INV>(csub(a1,a3));
  a0 = cadd(t0,t2); a1 = cadd(t1,t3); a2 = csub(t0,t2); a3 = csub(t1,t3);
}
__device__ __forceinline__ int SLOT16(int k){ return 4*(k&3) + (k>>2); }
template<int INV> __device__ __forceinline__ c32 twg(const float2* ltw, int idx){
  float2 w = ltw[idx & 255];
  return INV ? make_float2(w.x, w.y) : make_float2(w.x, -w.y);
}
template<int INV> __device__ __forceinline__ void fft16r(c32 v[16], const float2* ltw){
#pragma unroll
  for (int bp = 0; bp < 4; bp++) dft4<INV>(v[bp], v[4+bp], v[8+bp], v[12+bp]);
#pragma unroll
  for (int c = 1; c < 4; c++)
#pragma unroll
    for (int bp = 1; bp < 4; bp++)
      v[4*c+bp] = cmul(v[4*c+bp], twg<INV>(ltw, 16*bp*c));
#pragma unroll
  for (int c = 0; c < 4; c++) dft4<INV>(v[4*c], v[4*c+1], v[4*c+2], v[4*c+3]);
}
template<int INV>
__device__ __forceinline__ void fft256_core(c32 v[16], int b, c32* tile, const float2* ltw){
  fft16r<INV>(v, ltw);
#pragma unroll
  for (int c = 0; c < 16; c++){
    c32 g = (c && b) ? cmul(v[SLOT16(c)], twg<INV>(ltw, b*c)) : v[SLOT16(c)];
    tile[c*17 + b] = g;
  }
  __syncthreads();
#pragma unroll
  for (int j = 0; j < 16; j++) v[j] = tile[b*17 + j];
  fft16r<INV>(v, ltw);
}

// ---------- precompute tables ----------
__global__ void k_tw(float2* __restrict__ tw){
  int m = threadIdx.x;
  double ang = 6.283185307179586 * (double)m / 256.0;
  tw[m] = make_float2((float)cos(ang), (float)sin(ang));
}

// P2 layout: [io][y][10 c32 slots], l in 0..8 (slot 9 pad) -> 80B rows
__global__ void k_p2(const float* __restrict__ p2r, const float* __restrict__ p2i, c32* __restrict__ P2){
  int idx = blockIdx.x * 256 + threadIdx.x;   // io*NYF + y
  if (idx >= NIO * NYF) return;
  int io = idx / NYF, y = idx - io * NYF;
  c32* row = P2 + (size_t)idx * 10;
#pragma unroll
  for (int l = 0; l < 9; l++){
    float a = -p2r[io*9 + l];
    float b = 6.2831853071795864f * (float)y - p2i[io*9 + l];
    float inv = 1.0f / fmaf(a, a, b * b);
    row[l] = make_float2(a * inv, -b * inv);
  }
}

__global__ void k_e1(const float* __restrict__ p1r, const float* __restrict__ p1i, c32* __restrict__ E1){
  int idx = blockIdx.x * 256 + threadIdx.x;
  int z = idx & 255; int iok = idx >> 8;
  float t = (float)z * (1.0f / 256.0f);
  float er = expf(p1r[iok] * t);
  float s, c; sincosf(p1i[iok] * t, &s, &c);
  E1[idx] = make_float2(er * c, er * s);
}

// ---------- forward: rfft along n2 (paired rows), write alpha[(bi*129+y)*256+n1], scaled 1/65536 ----------
__global__ __launch_bounds__(256) void k_fwd_y(const float* __restrict__ x, const float2* __restrict__ tw,
                                               c32* __restrict__ alpha){
  __shared__ c32 tile[16*272];
  __shared__ float2 ltw[256];
  int t = threadIdx.x;
  ltw[t] = tw[t];
  int bi = blockIdx.x >> 3;
  int n1c = (blockIdx.x & 7) << 5;
  int row = t >> 4, b = t & 15;
  const float* xe = x + ((size_t)bi * 256 + n1c + 2 * row) * 256;
  c32 v[16];
#pragma unroll
  for (int a = 0; a < 16; a++)
    v[a] = make_float2(xe[16*a + b], xe[256 + 16*a + b]);
  __syncthreads();
  fft256_core<0>(v, b, tile + row*272, ltw);
  __syncthreads();
#pragma unroll
  for (int d = 0; d < 16; d++)
    tile[row*272 + b + 16*d] = v[SLOT16(d)];
  __syncthreads();
  const float sc = 0.5f / 65536.0f;
#pragma unroll
  for (int j = 0; j < 8; j++){
    int item = t + 256*j;
    int h = item & 127, r2 = item >> 7;
    c32* Zb = tile + r2*272;
    if (h == 0){
      c32 z0 = Zb[0], z1 = Zb[128];
      Zb[0]   = make_float2(z0.x * (2.0f*sc), z0.y * (2.0f*sc));
      Zb[128] = make_float2(z1.x * (2.0f*sc), z1.y * (2.0f*sc));
    } else {
      c32 zk = Zb[h], zm = Zb[256 - h];
      c32 A = make_float2(sc*(zk.x + zm.x), sc*(zk.y - zm.y));
      c32 B = make_float2(sc*(zk.y + zm.y), sc*(zm.x - zk.x));
      Zb[h] = A; Zb[256 - h] = B;
    }
  }
  __syncthreads();
  for (int j = 0; j < 17; j++){
    int idx = t + 256*j;
    if (idx >= 129*32) break;
    int y = idx >> 5, n1i = idx & 31;
    c32* Zb = tile + (n1i >> 1)*272;
    c32 val;
    if ((n1i & 1) == 0)
      val = (y == 0) ? make_float2(Zb[0].x, 0.0f)
          : (y == 128) ? make_float2(Zb[128].x, 0.0f) : Zb[y];
    else
      val = (y == 0) ? make_float2(Zb[0].y, 0.0f)
          : (y == 128) ? make_float2(Zb[128].y, 0.0f) : Zb[256 - y];
    alpha[((size_t)bi * 129 + y) * 256 + n1c + n1i] = val;
  }
}

// ---------- complex FFT-256 on contiguous rows, in place ----------
template<int INV>
__global__ __launch_bounds__(256) void k_fft_x(const float2* __restrict__ tw, c32* __restrict__ buf){
  __shared__ c32 tile[16*272];
  __shared__ float2 ltw[256];
  int t = threadIdx.x;
  ltw[t] = tw[t];
  int row = t >> 4, b = t & 15;
  c32* p = buf + ((size_t)blockIdx.x * 16 + row) * 256;
  c32 v[16];
#pragma unroll
  for (int a = 0; a < 16; a++) v[a] = p[16*a + b];
  __syncthreads();
  fft256_core<INV>(v, b, tile + row*272, ltw);
#pragma unroll
  for (int d = 0; d < 16; d++) p[b + 16*d] = v[SLOT16(d)];
}

// ---------- inverse rfft along y (paired z-columns) + bias, writes out ----------
__global__ __launch_bounds__(256) void k_inv_y(const c32* __restrict__ r1, const float* __restrict__ bias,
                                               const float2* __restrict__ tw, float* __restrict__ out){
  __shared__ c32 tile[16*272];
  __shared__ float2 ltw[256];
  c32* SA = tile;
  int t = threadIdx.x;
  ltw[t] = tw[t];
  int bo = blockIdx.x >> 3;
  int z0 = (blockIdx.x & 7) << 5;
  for (int j = 0; j < 17; j++){
    int idx = t + 256*j;
    if (idx >= 129*32) break;
    int y = idx >> 5, zi = idx & 31;
    SA[y*33 + zi] = r1[((size_t)bo * 129 + y) * 256 + z0 + zi];
  }
  __syncthreads();
  int p = t >> 4, b = t & 15;
  c32 v[16];
#pragma unroll
  for (int a = 0; a < 16; a++){
    int k = 16*a + b;
    int m = (k <= 128) ? k : 256 - k;
    c32 A = SA[m*33 + 2*p], B = SA[m*33 + 2*p + 1];
    if (k == 0 || k == 128)  v[a] = make_float2(A.x, B.x);
    else if (k < 128)        v[a] = make_float2(A.x - B.y, A.y + B.x);
    else                     v[a] = make_float2(A.x + B.y, B.x - A.y);
  }
  __syncthreads();
  fft256_core<1>(v, b, tile + p*272, ltw);
  float bv = bias[bo & 31];
  float* o0 = out + ((size_t)bo * 256 + z0 + 2*p) * 256;
#pragma unroll
  for (int d = 0; d < 16; d++){
    c32 zz = v[SLOT16(d)];
    o0[b + 16*d]       = zz.x + bv;
    o0[256 + b + 16*d] = zz.y + bv;
  }
}

// ---------- mode mixing r1: poles on-the-fly, R2 staged in LDS, 4-y tile ----------
__global__ __launch_bounds__(256, 4) void k_r1(const c32* __restrict__ alpha,
                                               const float* __restrict__ rr, const float* __restrict__ ri,
                                               const float* __restrict__ p1r, const float* __restrict__ p1i,
                                               const c32* __restrict__ P2,
                                               c32* __restrict__ r1){
  __shared__ float4 R2r4[512], R2i4[512];    // [i*16+k] -> 4 y's
  int t = threadIdx.x;
  int j = blockIdx.x;
  int g = (j & 7) * 132 + (j >> 3);          // XCD-chunked
  int y4 = g >> 5, o = g & 31;               // y4: 0..32
  int y0 = y4 * 4;
  int yv = (y0 + 4 <= 129) ? 4 : (129 - y0);
  float* R2r = (float*)R2r4; float* R2i = (float*)R2i4;
#pragma unroll
  for (int e = 0; e < 8; e++){
    int flat = t + e * 256;                  // i*64 + k*4 + yy
    int i = flat >> 6, k = (flat >> 2) & 15, yy = flat & 3;
    int io = i * 32 + o;
    int iok = io * 16 + k;
    int ya = y0 + yy; if (ya > 128) ya = 128;
    float ar = 0.f, ai = 0.f;
#pragma unroll
    for (int l = 0; l < 9; l++){
      float rsr = rr[iok*9 + l], rsi = ri[iok*9 + l];
      c32 p2 = P2[((size_t)io * NYF + ya) * 10 + l];
      ar = fmaf(rsr, p2.x, ar); ar = fmaf(-rsi, p2.y, ar);
      ai = fmaf(rsr, p2.y, ai); ai = fmaf(rsi, p2.x, ai);
    }
    R2r[flat] = ar; R2i[flat] = ai;
  }
  __syncthreads();
  int x = t;
  float fx = (x < 128) ? (float)x : (float)(x - 256);
  float lamb = 6.2831853071795864f * fx;
  float acr[8][4], aci[8][4];
#pragma unroll
  for (int b = 0; b < 8; b++)
#pragma unroll
    for (int yy = 0; yy < 4; yy++){ acr[b][yy] = 0.f; aci[b][yy] = 0.f; }
  size_t yoff[4];
#pragma unroll
  for (int yy = 0; yy < 4; yy++){
    int ya = y0 + yy; if (ya > 128) ya = 128;
    yoff[yy] = (size_t)ya * 256;
  }
  for (int i = 0; i < 32; i++){
    int io = i * 32 + o;
    const float* pr = p1r + io * 16;
    const float* pim = p1i + io * 16;
    float hwr[4] = {0.f,0.f,0.f,0.f}, hwi[4] = {0.f,0.f,0.f,0.f};
#pragma unroll
    for (int k = 0; k < 16; k++){
      float a = -pr[k];
      float b = lamb - pim[k];
      float inv = 1.0f / fmaf(a, a, b * b);
      float px = a * inv, py = -b * inv;
      float4 r4 = R2r4[i*16 + k], i4 = R2i4[i*16 + k];
      hwr[0]=fmaf(px,r4.x,hwr[0]); hwr[0]=fmaf(-py,i4.x,hwr[0]);
      hwi[0]=fmaf(px,i4.x,hwi[0]); hwi[0]=fmaf( py,r4.x,hwi[0]);
      hwr[1]=fmaf(px,r4.y,hwr[1]); hwr[1]=fmaf(-py,i4.y,hwr[1]);
      hwi[1]=fmaf(px,i4.y,hwi[1]); hwi[1]=fmaf( py,r4.y,hwi[1]);
      hwr[2]=fmaf(px,r4.z,hwr[2]); hwr[2]=fmaf(-py,i4.z,hwr[2]);
      hwi[2]=fmaf(px,i4.z,hwi[2]); hwi[2]=fmaf( py,r4.z,hwi[2]);
      hwr[3]=fmaf(px,r4.w,hwr[3]); hwr[3]=fmaf(-py,i4.w,hwr[3]);
      hwi[3]=fmaf(px,i4.w,hwi[3]); hwi[3]=fmaf( py,r4.w,hwi[3]);
    }
    const c32* ab = alpha + (size_t)i * 129 * 256 + x;
#pragma unroll
    for (int b = 0; b < 8; b++){
      const c32* ap = ab + (size_t)b * 32 * 129 * 256;
#pragma unroll
      for (int yy = 0; yy < 4; yy++){
        c32 av = ap[yoff[yy]];
        acr[b][yy]=fmaf(av.x,hwr[yy],acr[b][yy]); acr[b][yy]=fmaf(-av.y,hwi[yy],acr[b][yy]);
        aci[b][yy]=fmaf(av.x,hwi[yy],aci[b][yy]); aci[b][yy]=fmaf( av.y,hwr[yy],aci[b][yy]);
      }
    }
  }
#pragma unroll
  for (int b = 0; b < 8; b++)
    for (int yy = 0; yy < yv; yy++)
      r1[(((size_t)(b*32 + o) * 129) + y0 + yy) * 256 + x] = make_float2(acr[b][yy], aci[b][yy]);
}

// ---------- r2[b,io,k,l]: phase1 scalar-P2 (SMEM pipe, zero LDS), phase2 transposed-T reads ----------
__global__ __launch_bounds__(256) void k_r2k(const c32* __restrict__ alpha,
                                             const float* __restrict__ p1r, const float* __restrict__ p1i,
                                             const c32* __restrict__ P2,
                                             const float* __restrict__ rr, const float* __restrict__ ri,
                                             c32* __restrict__ r2){
  __shared__ c32 Ts[256 * 12];      // [x][l], 9 + 3 pad -> 96B rows (16B aligned)
  int t = threadIdx.x;
  int j = blockIdx.x;               // 8192 = 8 XCD * 1024
  int bid = (j & 7) * 1024 + (j >> 3);  // same-bi (32 o's) consecutive per XCD
  int o = bid & 31; int bi = bid >> 5;
  int i = bi & 31;  int b = bi >> 5;
  int io = i * COut + o;
  { // phase 1: T[l][x=t] = sum_y alpha[bi,y,t] * P2row[y][l]; P2 reads are wave-uniform -> s_load
    float tr[9], ti[9];
#pragma unroll
    for (int l = 0; l < 9; l++){ tr[l] = 0.f; ti[l] = 0.f; }
    const c32* ap = alpha + (size_t)bi * NYF * 256 + t;
    const float* __restrict__ P2u = (const float*)(P2 + (size_t)io * NYF * 10);
    c32 a0 = ap[0], a1 = ap[256], a2 = ap[512], a3 = ap[768];
#define R2K_BODY(aa, Y, PF) { \
      const float* prw = P2u + (size_t)(Y) * 20; \
      float axr = (aa).x, ayi = (aa).y; \
      PF; \
      _Pragma("unroll") \
      for (int l = 0; l < 9; l++){ \
        float pc = prw[2*l], ps = prw[2*l+1]; \
        tr[l] = fmaf(axr, pc, tr[l]); tr[l] = fmaf(-ayi, ps, tr[l]); \
        ti[l] = fmaf(axr, ps, ti[l]); ti[l] = fmaf(ayi, pc, ti[l]); } }
    for (int yb = 0; yb < 128; yb += 4){
      R2K_BODY(a0, yb+0, a0 = ap[(size_t)(yb+4)*256]);
      R2K_BODY(a1, yb+1, a1 = ap[(size_t)(yb+5)*256]);
      R2K_BODY(a2, yb+2, a2 = ap[(size_t)(yb+6)*256]);
      R2K_BODY(a3, yb+3, a3 = ap[(size_t)(yb+7)*256]);
    }
    R2K_BODY(a0, 128, );
#undef R2K_BODY
    c32* myrow = Ts + t * 12;
#pragma unroll
    for (int l = 0; l < 9; l++) myrow[l] = make_float2(tr[l], ti[l]);
  }
  __syncthreads();
  { // phase 2: r2[k,l] = -res[k,l] * sum_x P1[k,x]*T[l,x]
    int k = t >> 4, c = t & 15;
    float pa = -p1r[io*16 + k];
    float pb =  p1i[io*16 + k];
    float gr[9], gi[9];
#pragma unroll
    for (int l = 0; l < 9; l++){ gr[l] = 0.f; gi[l] = 0.f; }
#pragma unroll 4
    for (int jj = 0; jj < 16; jj++){
      int xx = c + 16*jj;
      float fx = (xx < 128) ? (float)xx : (float)(xx - 256);
      float bb = 6.2831853071795864f * fx - pb;
      float inv = 1.0f / fmaf(pa, pa, bb * bb);
      float px = pa * inv, py = -bb * inv;
      const c32* trow = Ts + xx * 12;
      float4 q0 = *(const float4*)(trow + 0);
      float4 q1 = *(const float4*)(trow + 2);
      float4 q2 = *(const float4*)(trow + 4);
      float4 q3 = *(const float4*)(trow + 6);
      c32    q4 = trow[8];
      float Trv[9] = {q0.x, q0.z, q1.x, q1.z, q2.x, q2.z, q3.x, q3.z, q4.x};
      float Tiv[9] = {q0.y, q0.w, q1.y, q1.w, q2.y, q2.w, q3.y, q3.w, q4.y};
#pragma unroll
      for (int l = 0; l < 9; l++){
        gr[l] = fmaf(px, Trv[l], gr[l]); gr[l] = fmaf(-py, Tiv[l], gr[l]);
        gi[l] = fmaf(px, Tiv[l], gi[l]); gi[l] = fmaf( py, Trv[l], gi[l]);
      }
    }
#pragma unroll
    for (int s = 1; s < 16; s <<= 1){
#pragma unroll
      for (int l = 0; l < 9; l++){
        gr[l] += __shfl_xor(gr[l], s, 64);
        gi[l] += __shfl_xor(gi[l], s, 64);
      }
    }
    if (c == 0){
#pragma unroll
      for (int l = 0; l < 9; l++){
        float resr = rr[(io*16 + k)*9 + l];
        float resi = ri[(io*16 + k)*9 + l];
        r2[((size_t)b * NIO + io) * NKL + k*9 + l] =
          make_float2(-(resr*gr[l] - resi*gi[l]), -(resr*gi[l] + resi*gr[l]));
      }
    }
  }
}

// ---------- x2 path: split-bf16 MFMA GEMM pipeline ----------
__global__ __launch_bounds__(256) void k_e2b(const float* __restrict__ p2r, const float* __restrict__ p2i,
                                             unsigned int* __restrict__ B){
  int j = blockIdx.x;
  int o = j & 31, ic = j >> 5;
  int w = threadIdx.x;
  float tt = (float)w * (1.0f / 256.0f);
  unsigned int* brow = B + ((size_t)o * 256 + w) * 576;   // 576 uints = 1152 halves
#pragma unroll
  for (int ii = 0; ii < 4; ii++){
    int i = ic * 4 + ii;
    int io = i * 32 + o;
#pragma unroll
    for (int l = 0; l < 9; l++){
      float pr = p2r[io*9 + l], pi = p2i[io*9 + l];
      float er = expf(pr * tt);
      float s, c; sincosf(pi * tt, &s, &c);
      float vr = er * c, vi = -er * s;
      unsigned short rh, rl, ih, il;
      split_bf(vr, rh, rl); split_bf(vi, ih, il);
      brow[i*9 + l]       = (unsigned int)rh | ((unsigned int)ih << 16);
      brow[288 + i*9 + l] = (unsigned int)rl | ((unsigned int)il << 16);
    }
  }
}

__global__ __launch_bounds__(256) void k_v(const c32* __restrict__ r2, const c32* __restrict__ E1,
                                           unsigned int* __restrict__ Ahi, unsigned int* __restrict__ Alo){
  int t = threadIdx.x;                 // z
  int j = blockIdx.x;                  // 1024
  int o = j & 31;
  int rest = j >> 5;                   // 0..31
  int b = rest & 7, ic = rest >> 3;    // ic 0..3
  size_t rowoff = ((size_t)o * 2048 + b * 256 + t) * 288;
  unsigned int* AH = Ahi + rowoff;
  unsigned int* AL = Alo + rowoff;
#pragma unroll 1
  for (int ii = 0; ii < 8; ii++){
    int i = ic * 8 + ii;
    int io = i * 32 + o;
    const c32* e1p = E1 + (size_t)io * 16 * 256 + t;
    c32 e[16];
#pragma unroll
    for (int k = 0; k < 16; k++) e[k] = e1p[(size_t)k * 256];
    const c32* rp = r2 + ((size_t)b * NIO + io) * NKL;
#pragma unroll
    for (int l = 0; l < 9; l++){
      c32 acc = make_float2(0.0f, 0.0f);
#pragma unroll
      for (int k = 0; k < 16; k++) acc = cfma(rp[k*9 + l], e[k], acc);
      unsigned short rh, rl, ih, il;
      split_bf(acc.x, rh, rl); split_bf(acc.y, ih, il);
      AH[i*9 + l] = (unsigned int)rh | ((unsigned int)ih << 16);
      AL[i*9 + l] = (unsigned int)rl | ((unsigned int)il << 16);
    }
  }
}

// GEMM: per o: C[2048][256] += Re(A*B^T), split-bf16 3-product schedule, 54 K-chunks of 32.
#define ALO_H 37748736u
__global__ __launch_bounds__(256) void k_x2m(const unsigned short* __restrict__ A,
                                             const unsigned short* __restrict__ B,
                                             float* __restrict__ out){
  __shared__ __align__(16) unsigned short At[128*32];
  __shared__ __align__(16) unsigned short Bt[128*32];
  int t = threadIdx.x;
  int j = blockIdx.x;                   // 1024
  int orig = (j & 7) * 128 + (j >> 3);  // same-o blocks grouped per XCD
  int o  = orig >> 5;
  int mb = (orig >> 1) & 15;
  int nb = orig & 1;
  const unsigned short* Ab = A + ((size_t)o*2048 + mb*128 + (t>>2))*576 + (t&3)*8;
  const unsigned short* Bb = B + ((size_t)o*256  + nb*128 + (t>>2))*1152 + (t&3)*8;
  int ln = t & 63;
  int wm = t >> 7, wn = (t >> 6) & 1;
  int lrow = ln & 15, lk = (ln >> 4) * 8;
  f32x4 acc[4][4];
#pragma unroll
  for (int mi = 0; mi < 4; mi++)
#pragma unroll
    for (int ni = 0; ni < 4; ni++) acc[mi][ni] = (f32x4){0.f,0.f,0.f,0.f};

  for (int ks = 0; ks < 54; ks++){
    int kA = ks % 18;
    int kB = ks % 36;
    const unsigned short* Ap = Ab + (ks >= 36 ? (size_t)ALO_H : 0) + (size_t)kA*32;
    __syncthreads();
    GLOAD16(At + (size_t)t*8,        Ap);
    GLOAD16(At + 2048 + (size_t)t*8, Ap + (size_t)64*576);
    GLOAD16(Bt + (size_t)t*8,        Bb + (size_t)kB*32);
    GLOAD16(Bt + 2048 + (size_t)t*8, Bb + (size_t)kB*32 + (size_t)64*1152);
    __syncthreads();
    bf16x8 av[4], bv[4];
#pragma unroll
    for (int mi = 0; mi < 4; mi++)
      av[mi] = *(const bf16x8*)(At + (wm*64 + mi*16 + lrow)*32 + lk);
#pragma unroll
    for (int ni = 0; ni < 4; ni++)
      bv[ni] = *(const bf16x8*)(Bt + (wn*64 + ni*16 + lrow)*32 + lk);
#pragma unroll
    for (int mi = 0; mi < 4; mi++)
#pragma unroll
      for (int ni = 0; ni < 4; ni++)
        acc[mi][ni] = __builtin_amdgcn_mfma_f32_16x16x32_bf16(av[mi], bv[ni], acc[mi][ni], 0, 0, 0);
  }
  int nglob = nb*128 + wn*64 + (ln & 15);
#pragma unroll
  for (int mi = 0; mi < 4; mi++){
#pragma unroll
    for (int r = 0; r < 4; r++){
      int m = mb*128 + wm*64 + mi*16 + (ln >> 4)*4 + r;
      int b = m >> 8, z = m & 255;
      float* op = out + (((size_t)(b*32 + o) * 256 + z) * 256) + nglob;
#pragma unroll
      for (int ni = 0; ni < 4; ni++)
        op[ni*16] += acc[mi][ni][r];
    }
  }
}

extern "C" void kernel_launch(void* const* d_in, const int* in_sizes, int n_in,
                              void* d_out, int out_size, void* d_ws, size_t ws_size,
                              hipStream_t stream){
  const float* x    = (const float*)d_in[0];
  const float* rr   = (const float*)d_in[1];
  const float* ri   = (const float*)d_in[2];
  const float* p1r  = (const float*)d_in[3];
  const float* p1i  = (const float*)d_in[4];
  const float* p2r  = (const float*)d_in[5];
  const float* p2i  = (const float*)d_in[6];
  const float* bias = (const float*)d_in[7];
  float* out = (float*)d_out;

  // ws layout (offsets unchanged from round 8; P2b grew into the adjacent dead hole)
  char* ws = (char*)d_ws;
  size_t off = 0;
  c32* alpha = (c32*)(ws + off); off += (size_t)NB * CIn * NYF * NN1 * sizeof(c32);   // 67.6 MB
  c32* r1b   = (c32*)(ws + off); off += (size_t)NB * COut * NYF * NN1 * sizeof(c32);  // 67.6 MB
  off += (size_t)NIO * NK1 * NN1 * sizeof(c32);                                       // (hole)
  c32* P2b   = (c32*)(ws + off); off += (size_t)NIO * NYF * 10 * sizeof(c32);         // 10.6 MB (into old R2b hole)
  off += (size_t)NIO * NK1 * NYF * sizeof(c32) - (size_t)NIO * NYF * 10 * sizeof(c32)
       + (size_t)NIO * NK2 * NYF * sizeof(c32);                                       // keep E1b offset identical
  c32* E1b   = (c32*)(ws + off); off += (size_t)NIO * NK1 * NN1 * sizeof(c32);        // 33.6 MB
  c32* r2b   = (c32*)(ws + off); off += (size_t)NB * NIO * NKL * sizeof(c32);         //  9.4 MB
  float2* tw = (float2*)(ws + off); off += 256 * sizeof(float2);
  unsigned short* Abf  = (unsigned short*)(ws + 0);
  unsigned short* E2bf = (unsigned short*)(ws + 150994944);

  k_tw<<<1, 256, 0, stream>>>(tw);
  k_p2<<<(NIO * NYF + 255) / 256, 256, 0, stream>>>(p2r, p2i, P2b);
  k_e1<<<NIO * NK1, 256, 0, stream>>>(p1r, p1i, E1b);

  k_fwd_y<<<NB * CIn * 8, 256, 0, stream>>>(x, tw, alpha);
  k_fft_x<0><<<NB * CIn * NYF / 16, 256, 0, stream>>>(tw, alpha);

  k_r1<<<1056, 256, 0, stream>>>(alpha, rr, ri, p1r, p1i, P2b, r1b);
  k_r2k<<<NB * CIn * COut, 256, 0, stream>>>(alpha, p1r, p1i, P2b, rr, ri, r2b);

  k_fft_x<1><<<NB * COut * NYF / 16, 256, 0, stream>>>(tw, r1b);
  k_inv_y<<<NB * COut * 8, 256, 0, stream>>>(r1b, bias, tw, out);

  k_e2b<<<256, 256, 0, stream>>>(p2r, p2i, (unsigned int*)E2bf);
  k_v<<<1024, 256, 0, stream>>>(r2b, E1b, (unsigned int*)Abf, (unsigned int*)(Abf + ALO_H));
  k_x2m<<<1024, 256, 0, stream>>>(Abf, E2bf, out);
}